// Round 1
// 488.193 us; speedup vs baseline: 1.0662x; 1.0662x over previous
//
#include <hip/hip_runtime.h>
#include <hip/hip_bf16.h>
#include <cstdint>
#include <cstddef>

// Problem constants (match reference)
#define NN      50000
#define IN_C    512
#define EE      800000
#define ETOT    850000      // E + N self-loops
#define HH      2
#define CC      64
#define HC      128
#define BB      64
#define OUTC    2
#define NEG_SLOPE 0.2f
#define BN_EPS  1e-5f

#define NBLK_SCAN ((NN + 255) / 256)   // 196

typedef __bf16 bf16x8 __attribute__((ext_vector_type(8)));
typedef float  f32x4  __attribute__((ext_vector_type(4)));

__device__ __forceinline__ unsigned f2bf(float f) {
    __bf16 b = (__bf16)f;                      // RNE convert
    return (unsigned)__builtin_bit_cast(unsigned short, b);
}

__device__ __forceinline__ void edge_sd(const int* __restrict__ ei, int e, int& s, int& d) {
    if (e < EE) { s = ei[e]; d = ei[EE + e]; }
    else        { s = e - EE; d = e - EE; }
}

// ================= CSR build (graph fixed; built once per launch, reused by both layers) =================
__global__ __launch_bounds__(256) void deg_kernel(const int* __restrict__ ei, int* __restrict__ deg)
{
    int e = blockIdx.x * 256 + threadIdx.x;
    if (e >= ETOT) return;
    int d = (e < EE) ? ei[EE + e] : (e - EE);
    atomicAdd(&deg[d], 1);
}

// --- hierarchical scan ---
__global__ __launch_bounds__(256) void bsum_kernel(const int* __restrict__ deg, int* __restrict__ bsum)
{
    int i = blockIdx.x * 256 + threadIdx.x;
    int v = (i < NN) ? deg[i] : 0;
    int lane = threadIdx.x & 63, wv = threadIdx.x >> 6;
#pragma unroll
    for (int o = 32; o > 0; o >>= 1) v += __shfl_down(v, o);
    __shared__ int ws[4];
    if (lane == 0) ws[wv] = v;
    __syncthreads();
    if (threadIdx.x == 0) bsum[blockIdx.x] = ws[0] + ws[1] + ws[2] + ws[3];
}

__global__ __launch_bounds__(256) void bscan_kernel(
    const int* __restrict__ bsum, int* __restrict__ bofs, int* __restrict__ rowp)
{
    int t = threadIdx.x;
    int lane = t & 63, wv = t >> 6;
    int v = (t < NBLK_SCAN) ? bsum[t] : 0;
    int x = v;
#pragma unroll
    for (int o = 1; o < 64; o <<= 1) {
        int y = __shfl_up(x, o);
        if (lane >= o) x += y;
    }
    __shared__ int ws[4];
    if (lane == 63) ws[wv] = x;
    __syncthreads();
    int wo = 0;
#pragma unroll
    for (int w = 0; w < 4; ++w) if (w < wv) wo += ws[w];
    if (t < NBLK_SCAN) bofs[t] = x + wo - v;     // exclusive
    if (t == 0) rowp[NN] = ETOT;
}

__global__ __launch_bounds__(256) void bapply_kernel(
    const int* __restrict__ deg, const int* __restrict__ bofs,
    int* __restrict__ rowp, int* __restrict__ cur)
{
    int i = blockIdx.x * 256 + threadIdx.x;
    int v = (i < NN) ? deg[i] : 0;
    int lane = threadIdx.x & 63, wv = threadIdx.x >> 6;
    int x = v;
#pragma unroll
    for (int o = 1; o < 64; o <<= 1) {
        int y = __shfl_up(x, o);
        if (lane >= o) x += y;
    }
    __shared__ int ws[4];
    if (lane == 63) ws[wv] = x;
    __syncthreads();
    int wo = 0;
#pragma unroll
    for (int w = 0; w < 4; ++w) if (w < wv) wo += ws[w];
    if (i < NN) {
        int r = bofs[blockIdx.x] + x + wo - v;   // exclusive global
        rowp[i] = r; cur[i] = r;
    }
}

__global__ __launch_bounds__(256) void scatter_kernel(
    const int* __restrict__ ei, int* __restrict__ cur, int* __restrict__ esrc)
{
    int e = blockIdx.x * 256 + threadIdx.x;
    if (e >= ETOT) return;
    int s, d; edge_sd(ei, e, s, d);
    int pos = atomicAdd(&cur[d], 1);
    esrc[pos] = s;
}

// ================= W -> bf16 MFMA fragment order =================
__global__ __launch_bounds__(256) void wfrag_kernel(
    const float* __restrict__ W, unsigned short* __restrict__ Wf, int K)
{
    int t = blockIdx.x * 256 + threadIdx.x;       // t = frag*64 + lane
    if (t >= K * 16) return;                      // (K/32)*8*64 == K*16
    int lane = t & 63, frag = t >> 6;
    int kblk = frag >> 3, nt = frag & 7;
    int quad = lane >> 4, ln = lane & 15;
    int kbase = kblk * 32 + quad * 8;
    int n = nt * 16 + ln;
    unsigned short u[8];
#pragma unroll
    for (int j = 0; j < 8; ++j)
        u[j] = (unsigned short)f2bf(W[(size_t)(kbase + j) * HC + n]);
    ushort4 a; a.x = u[0]; a.y = u[1]; a.z = u[2]; a.w = u[3];
    ushort4 b; b.x = u[4]; b.y = u[5]; b.z = u[6]; b.w = u[7];
    *(ushort4*)(Wf + (size_t)t * 8)     = a;
    *(ushort4*)(Wf + (size_t)t * 8 + 4) = b;
}

// ================= barrier-free per-wave MFMA GEMM + fused alpha + bf16 pack =================
// Each wave owns 16 rows x 128 cols. K is a template constant -> K-loop fully unrolled,
// A is register-prefetched 4 steps deep (depth-1 was leaving a full HBM latency exposed
// per step at only ~3 waves/SIMD), B-frags are double-buffered from L2.
// __launch_bounds__(256,3) pins 12 waves/CU while allowing ~170 VGPR.
template<int K, bool AFFINE>
__global__ __launch_bounds__(256, 3) void mfma_gemm_kernel(
    const float* __restrict__ A, const unsigned short* __restrict__ Wf,
    const float* __restrict__ atts, const float* __restrict__ attd,
    unsigned* __restrict__ hb, float* __restrict__ as_, float* __restrict__ ad_,
    const float* __restrict__ sc, const float* __restrict__ sh)
{
    constexpr int NSTEP = K >> 5;
    constexpr int AD = (NSTEP < 4) ? NSTEP : 4;   // A-prefetch depth

    const int tid  = threadIdx.x;
    const int wave = tid >> 6, lane = tid & 63;
    const int quad = lane >> 4, ln = lane & 15;
    const int m0 = blockIdx.x * 64;
    const int myrow = m0 + wave * 16 + ln;        // row this lane's A-frag comes from
    const bool rok = (myrow < NN);
    const float* arow = A + (size_t)(rok ? myrow : 0) * K + quad * 8;
    const unsigned short* wbase = Wf + lane * 8;

    f32x4 acc[8];
#pragma unroll
    for (int nt = 0; nt < 8; ++nt) acc[nt] = (f32x4){0.f, 0.f, 0.f, 0.f};

    // prologue: A-prefetch pipeline, AD steps deep
    const float4 z4 = make_float4(0.f, 0.f, 0.f, 0.f);
    float4 pa[AD], pb[AD];
#pragma unroll
    for (int d = 0; d < AD; ++d) {
        if (rok) {
            pa[d] = *(const float4*)(arow + d * 32);
            pb[d] = *(const float4*)(arow + d * 32 + 4);
        } else { pa[d] = z4; pb[d] = z4; }
    }

    // B double buffer: step 0
    bf16x8 bfr[2][8];
#pragma unroll
    for (int nt = 0; nt < 8; ++nt) bfr[0][nt] = *(const bf16x8*)(wbase + nt * 512);

#pragma unroll
    for (int ks = 0; ks < NSTEP; ++ks) {
        const int cur = ks & 1;
        // prefetch next step's B-frags (in flight across this step's MFMAs)
        if (ks + 1 < NSTEP) {
            const unsigned short* wfp = wbase + (size_t)(ks + 1) * 4096;
#pragma unroll
            for (int nt = 0; nt < 8; ++nt)
                bfr[cur ^ 1][nt] = *(const bf16x8*)(wfp + nt * 512);
        }

        // convert this step's A-frag (loaded AD steps ago)
        float4 ca = pa[ks % AD], cb = pb[ks % AD];
        float va[8] = {ca.x, ca.y, ca.z, ca.w, cb.x, cb.y, cb.z, cb.w};
        if (AFFINE) {
            const int kk = ks * 32 + quad * 8;
            const float4 s0 = *(const float4*)(sc + kk), s1 = *(const float4*)(sc + kk + 4);
            const float4 h0 = *(const float4*)(sh + kk), h1 = *(const float4*)(sh + kk + 4);
            va[0] = fmaxf(fmaf(s0.x, va[0], h0.x), 0.f);
            va[1] = fmaxf(fmaf(s0.y, va[1], h0.y), 0.f);
            va[2] = fmaxf(fmaf(s0.z, va[2], h0.z), 0.f);
            va[3] = fmaxf(fmaf(s0.w, va[3], h0.w), 0.f);
            va[4] = fmaxf(fmaf(s1.x, va[4], h1.x), 0.f);
            va[5] = fmaxf(fmaf(s1.y, va[5], h1.y), 0.f);
            va[6] = fmaxf(fmaf(s1.z, va[6], h1.z), 0.f);
            va[7] = fmaxf(fmaf(s1.w, va[7], h1.w), 0.f);
        }
        union { bf16x8 v; unsigned short u[8]; } af;
#pragma unroll
        for (int j = 0; j < 8; ++j) af.u[j] = (unsigned short)f2bf(va[j]);

        // refill the just-freed A slot with step ks+AD
        if (ks + AD < NSTEP && rok) {
            const float* nx = arow + (size_t)(ks + AD) * 32;
            pa[ks % AD] = *(const float4*)nx;
            pb[ks % AD] = *(const float4*)(nx + 4);
        }

#pragma unroll
        for (int nt = 0; nt < 8; ++nt)
            acc[nt] = __builtin_amdgcn_mfma_f32_16x16x32_bf16(af.v, bfr[cur][nt], acc[nt], 0, 0, 0);
    }

    // epilogue: pack bf16 pairs + fused attention logits; C/D layout col=ln, row=quad*4+r
    float wsv[8], wdv[8];
#pragma unroll
    for (int nt = 0; nt < 8; ++nt) { wsv[nt] = atts[nt * 16 + ln]; wdv[nt] = attd[nt * 16 + ln]; }

    const int mbase = m0 + wave * 16 + quad * 4;
#pragma unroll
    for (int r = 0; r < 4; ++r) {
        int m = mbase + r;
        bool ok = (m < NN);
        float ps0 = 0.f, ps1 = 0.f, pd0 = 0.f, pd1 = 0.f;
#pragma unroll
        for (int nt = 0; nt < 8; ++nt) {
            float v = acc[nt][r];
            if (nt < 4) { ps0 = fmaf(v, wsv[nt], ps0); pd0 = fmaf(v, wdv[nt], pd0); }
            else        { ps1 = fmaf(v, wsv[nt], ps1); pd1 = fmaf(v, wdv[nt], pd1); }
        }
#pragma unroll
        for (int nt = 0; nt < 4; ++nt) {
            unsigned pk = f2bf(acc[nt][r]) | (f2bf(acc[nt + 4][r]) << 16);
            if (ok) hb[(size_t)m * 64 + nt * 16 + ln] = pk;
        }
#pragma unroll
        for (int o = 8; o > 0; o >>= 1) {
            ps0 += __shfl_down(ps0, o); ps1 += __shfl_down(ps1, o);
            pd0 += __shfl_down(pd0, o); pd1 += __shfl_down(pd1, o);
        }
        if (ok && ln == 0) {
            *(float2*)&as_[m * 2] = make_float2(ps0, ps1);
            *(float2*)&ad_[m * 2] = make_float2(pd0, pd1);
        }
    }
}

// ================= fused segment-softmax + aggregate: one wave per dst node =================
// exp/leaky/denominator are computed VECTORIZED per-lane in the chunk phase (they only
// depend on per-edge logits); the serial broadcast loop is just shfl + gather + 2 FMA,
// unrolled 2 edges/iter for load-level parallelism. Denominator via butterfly at the end.
__global__ __launch_bounds__(256) void gat_agg_kernel(
    const int* __restrict__ rowp, const int* __restrict__ esrc,
    const float* __restrict__ as_, const float* __restrict__ ad_,
    const unsigned* __restrict__ hb, float* __restrict__ out)
{
    int node = (blockIdx.x * 256 + threadIdx.x) >> 6;
    int lane = threadIdx.x & 63;
    if (node >= NN) return;
    int beg = rowp[node], end = rowp[node + 1];
    float2 adv = *(const float2*)&ad_[node * 2];

    float l0 = 0.f, l1 = 0.f, a0 = 0.f, a1 = 0.f;

    for (int j0 = beg; j0 < end; j0 += 64) {
        int nj = min(64, end - j0);
        int   sl  = 0;
        float p0l = 0.f, p1l = 0.f;
        if (j0 + lane < end) {
            sl = esrc[j0 + lane];
            float2 t = *(const float2*)&as_[sl * 2];
            float e0 = t.x + adv.x; e0 = fmaxf(e0, NEG_SLOPE * e0);
            float e1 = t.y + adv.y; e1 = fmaxf(e1, NEG_SLOPE * e1);
            p0l = __expf(e0); p1l = __expf(e1);
        }
        l0 += p0l; l1 += p1l;          // per-lane partial denominator

        int j = 0;
        for (; j + 2 <= nj; j += 2) {
            int sA = __shfl(sl, j), sB = __shfl(sl, j + 1);
            unsigned uA = hb[(size_t)sA * 64 + lane];
            unsigned uB = hb[(size_t)sB * 64 + lane];
            float pA0 = __shfl(p0l, j),     pA1 = __shfl(p1l, j);
            float pB0 = __shfl(p0l, j + 1), pB1 = __shfl(p1l, j + 1);
            a0 = fmaf(pA0, __uint_as_float(uA << 16), a0);
            a1 = fmaf(pA1, __uint_as_float(uA & 0xffff0000u), a1);
            a0 = fmaf(pB0, __uint_as_float(uB << 16), a0);
            a1 = fmaf(pB1, __uint_as_float(uB & 0xffff0000u), a1);
        }
        if (j < nj) {
            int s = __shfl(sl, j);
            unsigned u = hb[(size_t)s * 64 + lane];
            float p0 = __shfl(p0l, j), p1 = __shfl(p1l, j);
            a0 = fmaf(p0, __uint_as_float(u << 16), a0);
            a1 = fmaf(p1, __uint_as_float(u & 0xffff0000u), a1);
        }
    }

#pragma unroll
    for (int o = 1; o < 64; o <<= 1) {
        l0 += __shfl_xor(l0, o); l1 += __shfl_xor(l1, o);
    }
    out[(size_t)node * HC + lane]      = a0 / l0;
    out[(size_t)node * HC + 64 + lane] = a1 / l1;
}

// ================= BN stats =================
__global__ __launch_bounds__(256) void bn_stats_kernel(
    const float* __restrict__ x, float* __restrict__ stats)
{
    int c = threadIdx.x & 127;
    int half = threadIdx.x >> 7;
    float s = 0.f, sq = 0.f;
    for (int r = blockIdx.x * 2 + half; r < NN; r += gridDim.x * 2) {
        float v = x[(size_t)r * HC + c];
        s += v; sq += v * v;
    }
    __shared__ float ls[256], lq[256];
    ls[threadIdx.x] = s; lq[threadIdx.x] = sq;
    __syncthreads();
    if (half == 0) {
        s += ls[threadIdx.x + 128];
        sq += lq[threadIdx.x + 128];
        atomicAdd(&stats[c], s);
        atomicAdd(&stats[128 + c], sq);
    }
}

__global__ void bn_params_kernel(
    const float* __restrict__ stats, const float* __restrict__ gamma,
    const float* __restrict__ beta, float* __restrict__ sc, float* __restrict__ sh)
{
    int c = threadIdx.x;
    const float inv_n = 1.0f / (float)NN;
    float mu = stats[c] * inv_n;
    float var = stats[128 + c] * inv_n - mu * mu;
    float rs = rsqrtf(var + BN_EPS);
    float s = gamma[c] * rs;
    sc[c] = s;
    sh[c] = beta[c] - mu * s;
}

// ================= pool: 64 rows/block (782 blocks), flush-on-graph-change =================
__global__ __launch_bounds__(256) void pool_kernel(
    const float* __restrict__ x, const float* __restrict__ sc,
    const float* __restrict__ sh, const int* __restrict__ batch,
    float* __restrict__ pool, float* __restrict__ cnt)
{
    int c = threadIdx.x & 127;
    int half = threadIdx.x >> 7;
    int r0 = blockIdx.x * 64;
    int rend = min(r0 + 64, NN);
    float s = sc[c], b = sh[c];
    int cur = -1; float acc = 0.f, ccount = 0.f;
    for (int r = r0 + half; r < rend; r += 2) {
        int g = batch[r];
        if (g != cur) {
            if (cur >= 0) {
                atomicAdd(&pool[cur * HC + c], acc);
                if (c == 0) atomicAdd(&cnt[cur], ccount);
            }
            cur = g; acc = 0.f; ccount = 0.f;
        }
        float v = x[(size_t)r * HC + c];
        acc += fmaxf(fmaf(s, v, b), 0.f);
        ccount += 1.f;
    }
    if (cur >= 0) {
        atomicAdd(&pool[cur * HC + c], acc);
        if (c == 0) atomicAdd(&cnt[cur], ccount);
    }
}

// ================= final linear: [64,128]@[128,2] + blin =================
__global__ void final_kernel(
    const float* __restrict__ pool, const float* __restrict__ cnt,
    const float* __restrict__ Wlin, const float* __restrict__ blin,
    float* __restrict__ outp)
{
    int t = threadIdx.x;               // 128 threads
    int b = t >> 1, oc = t & 1;
    float inv = 1.f / fmaxf(cnt[b], 1.f);
    float s = blin[oc];
    for (int c = 0; c < HC; ++c)
        s += pool[b * HC + c] * inv * Wlin[c * 2 + oc];
    outp[b * 2 + oc] = s;
}

// ================= workspace layout =================
// floats
static constexpr size_t OFF_OUT   = 0;                        // [N*HC]
static constexpr size_t OFF_AS    = OFF_OUT + (size_t)NN*HC;  // [N*2]
static constexpr size_t OFF_AD    = OFF_AS  + (size_t)NN*HH;
static constexpr size_t OFF_ST1   = OFF_AD  + (size_t)NN*HH;  // zero from here: [256]
static constexpr size_t OFF_ST2   = OFF_ST1 + 256;
static constexpr size_t OFF_SC1   = OFF_ST2 + 256;            // [128]
static constexpr size_t OFF_SH1   = OFF_SC1 + 128;
static constexpr size_t OFF_SC2   = OFF_SH1 + 128;
static constexpr size_t OFF_SH2   = OFF_SC2 + 128;
static constexpr size_t OFF_POOL  = OFF_SH2 + 128;            // [B*HC]
static constexpr size_t OFF_CNT   = OFF_POOL+ (size_t)BB*HC;  // [B]
static constexpr size_t OFF_ZEND  = OFF_CNT + BB;             // end of zeroed float region
// ints (after float region)
static constexpr size_t IOFF_DEG  = 0;                        // [N]  (zeroed)
static constexpr size_t IOFF_ROWP = IOFF_DEG  + NN;           // [N+1]
static constexpr size_t IOFF_CUR  = IOFF_ROWP + NN + 1;       // [N]
static constexpr size_t IOFF_BSUM = IOFF_CUR  + NN;           // [NBLK_SCAN]
static constexpr size_t IOFF_BOFS = IOFF_BSUM + NBLK_SCAN;    // [NBLK_SCAN]
static constexpr size_t IOFF_ESRC = IOFF_BOFS + NBLK_SCAN;    // [ETOT]
static constexpr size_t IOFF_HB   = (IOFF_ESRC + ETOT + 3) & ~(size_t)3;  // [N*64] uints
static constexpr size_t IOFF_WF1  = IOFF_HB + (size_t)NN*64;  // [512*64] ints
static constexpr size_t IOFF_WF2  = IOFF_WF1 + (size_t)IN_C*64; // [128*64] ints
static constexpr size_t IOFF_END  = IOFF_WF2 + (size_t)HC*64;

extern "C" void kernel_launch(void* const* d_in, const int* in_sizes, int n_in,
                              void* d_out, int out_size, void* d_ws, size_t ws_size,
                              hipStream_t stream)
{
    const float* x       = (const float*)d_in[0];
    const int*   ei      = (const int*)  d_in[1];
    const int*   batch   = (const int*)  d_in[2];
    const float* W1      = (const float*)d_in[3];
    const float* atts1   = (const float*)d_in[4];
    const float* attd1   = (const float*)d_in[5];
    const float* gamma1  = (const float*)d_in[7];
    const float* beta1   = (const float*)d_in[8];
    const float* W2      = (const float*)d_in[9];
    const float* atts2   = (const float*)d_in[10];
    const float* attd2   = (const float*)d_in[11];
    const float* gamma2  = (const float*)d_in[13];
    const float* beta2   = (const float*)d_in[14];
    const float* Wlin    = (const float*)d_in[15];
    const float* blin    = (const float*)d_in[16];
    float* outp = (float*)d_out;

    float* ws    = (float*)d_ws;
    float* out   = ws + OFF_OUT;
    float* as_   = ws + OFF_AS;
    float* ad_   = ws + OFF_AD;
    float* st1   = ws + OFF_ST1;
    float* st2   = ws + OFF_ST2;
    float* sc1   = ws + OFF_SC1;
    float* sh1   = ws + OFF_SH1;
    float* sc2   = ws + OFF_SC2;
    float* sh2   = ws + OFF_SH2;
    float* pool  = ws + OFF_POOL;
    float* cnt   = ws + OFF_CNT;

    int* iws  = (int*)(ws + OFF_ZEND);
    int* deg  = iws + IOFF_DEG;
    int* rowp = iws + IOFF_ROWP;
    int* curp = iws + IOFF_CUR;
    int* bsum = iws + IOFF_BSUM;
    int* bofs = iws + IOFF_BOFS;
    int* esrc = iws + IOFF_ESRC;
    unsigned* hb = (unsigned*)(iws + IOFF_HB);
    unsigned short* Wf1 = (unsigned short*)(iws + IOFF_WF1);
    unsigned short* Wf2 = (unsigned short*)(iws + IOFF_WF2);

    const int EDGE_BLK  = (ETOT + 255) / 256;
    const int GEMM_BLK  = (NN + 63) / 64;        // 782
    const int WAVE_BLK  = (NN + 3) / 4;          // 1 wave per node, 4 waves/block
    const int POOL_BLK  = (NN + 63) / 64;        // 782: 64 rows/block

    // zero: bn-stats/pool/cnt float region + deg
    hipMemsetAsync(st1, 0, (OFF_ZEND - OFF_ST1) * sizeof(float), stream);
    hipMemsetAsync(deg, 0, NN * sizeof(int), stream);

    // ----- weight fragment packs + CSR build (shared by both layers) -----
    wfrag_kernel<<<(IN_C * 16 + 255) / 256, 256, 0, stream>>>(W1, Wf1, IN_C);
    wfrag_kernel<<<(HC   * 16 + 255) / 256, 256, 0, stream>>>(W2, Wf2, HC);
    deg_kernel<<<EDGE_BLK, 256, 0, stream>>>(ei, deg);
    bsum_kernel<<<NBLK_SCAN, 256, 0, stream>>>(deg, bsum);
    bscan_kernel<<<1, 256, 0, stream>>>(bsum, bofs, rowp);
    bapply_kernel<<<NBLK_SCAN, 256, 0, stream>>>(deg, bofs, rowp, curp);
    scatter_kernel<<<EDGE_BLK, 256, 0, stream>>>(ei, curp, esrc);

    // ----- layer 1 (GEMM + fused alpha + bf16 pack) -----
    mfma_gemm_kernel<IN_C, false><<<GEMM_BLK, 256, 0, stream>>>(
        x, Wf1, atts1, attd1, hb, as_, ad_, nullptr, nullptr);
    gat_agg_kernel<<<WAVE_BLK, 256, 0, stream>>>(rowp, esrc, as_, ad_, hb, out);
    bn_stats_kernel<<<512, 256, 0, stream>>>(out, st1);
    bn_params_kernel<<<1, 128, 0, stream>>>(st1, gamma1, beta1, sc1, sh1);

    // ----- layer 2 (BN1-affine+ReLU fused into GEMM2 A-load) -----
    mfma_gemm_kernel<HC, true><<<GEMM_BLK, 256, 0, stream>>>(
        out, Wf2, atts2, attd2, hb, as_, ad_, sc1, sh1);
    gat_agg_kernel<<<WAVE_BLK, 256, 0, stream>>>(rowp, esrc, as_, ad_, hb, out);
    bn_stats_kernel<<<512, 256, 0, stream>>>(out, st2);
    bn_params_kernel<<<1, 128, 0, stream>>>(st2, gamma2, beta2, sc2, sh2);

    // ----- pool + final linear -----
    pool_kernel<<<POOL_BLK, 256, 0, stream>>>(out, sc2, sh2, batch, pool, cnt);
    final_kernel<<<1, 128, 0, stream>>>(pool, cnt, Wlin, blin, outp);
}

// Round 2
// 487.444 us; speedup vs baseline: 1.0679x; 1.0015x over previous
//
#include <hip/hip_runtime.h>
#include <hip/hip_bf16.h>
#include <cstdint>
#include <cstddef>

// Problem constants (match reference)
#define NN      50000
#define IN_C    512
#define EE      800000
#define ETOT    850000      // E + N self-loops
#define HH      2
#define CC      64
#define HC      128
#define BB      64
#define OUTC    2
#define NEG_SLOPE 0.2f
#define BN_EPS  1e-5f

#define NBLK_SCAN ((NN + 255) / 256)   // 196

// XCD binning for CSR build: 8 dst ranges, blockIdx%8 -> XCD (round-robin dispatch)
#define NXCD     8
#define NPX      ((NN + NXCD - 1) / NXCD)        // 6250 nodes per bin
#define EDGES_PER_SLOT 2048
#define NSLOT    ((ETOT + EDGES_PER_SLOT - 1) / EDGES_PER_SLOT)  // 416

typedef __bf16 bf16x8 __attribute__((ext_vector_type(8)));
typedef float  f32x4  __attribute__((ext_vector_type(4)));

__device__ __forceinline__ unsigned f2bf(float f) {
    __bf16 b = (__bf16)f;                      // RNE convert
    return (unsigned)__builtin_bit_cast(unsigned short, b);
}

// ================= CSR build (XCD-binned: each XCD owns a dst range; atomics and
// esrc writes stay in one L2 — no cross-XCD line ping-pong / write amplification) ==========
__global__ __launch_bounds__(256) void deg_kernel(const int* __restrict__ ei, int* __restrict__ deg)
{
    const int xcd  = blockIdx.x & (NXCD - 1);
    const int slot = blockIdx.x >> 3;
    const int lo = xcd * NPX, hi = lo + NPX;
    const int base = slot * EDGES_PER_SLOT;
#pragma unroll
    for (int it = 0; it < EDGES_PER_SLOT / 256; ++it) {
        int e = base + it * 256 + threadIdx.x;
        if (e < ETOT) {
            int d = (e < EE) ? ei[EE + e] : (e - EE);
            if (d >= lo && d < hi) atomicAdd(&deg[d], 1);
        }
    }
}

// --- hierarchical scan ---
__global__ __launch_bounds__(256) void bsum_kernel(const int* __restrict__ deg, int* __restrict__ bsum)
{
    int i = blockIdx.x * 256 + threadIdx.x;
    int v = (i < NN) ? deg[i] : 0;
    int lane = threadIdx.x & 63, wv = threadIdx.x >> 6;
#pragma unroll
    for (int o = 32; o > 0; o >>= 1) v += __shfl_down(v, o);
    __shared__ int ws[4];
    if (lane == 0) ws[wv] = v;
    __syncthreads();
    if (threadIdx.x == 0) bsum[blockIdx.x] = ws[0] + ws[1] + ws[2] + ws[3];
}

__global__ __launch_bounds__(256) void bscan_kernel(
    const int* __restrict__ bsum, int* __restrict__ bofs, int* __restrict__ rowp)
{
    int t = threadIdx.x;
    int lane = t & 63, wv = t >> 6;
    int v = (t < NBLK_SCAN) ? bsum[t] : 0;
    int x = v;
#pragma unroll
    for (int o = 1; o < 64; o <<= 1) {
        int y = __shfl_up(x, o);
        if (lane >= o) x += y;
    }
    __shared__ int ws[4];
    if (lane == 63) ws[wv] = x;
    __syncthreads();
    int wo = 0;
#pragma unroll
    for (int w = 0; w < 4; ++w) if (w < wv) wo += ws[w];
    if (t < NBLK_SCAN) bofs[t] = x + wo - v;     // exclusive
    if (t == 0) rowp[NN] = ETOT;
}

__global__ __launch_bounds__(256) void bapply_kernel(
    const int* __restrict__ deg, const int* __restrict__ bofs,
    int* __restrict__ rowp, int* __restrict__ cur)
{
    int i = blockIdx.x * 256 + threadIdx.x;
    int v = (i < NN) ? deg[i] : 0;
    int lane = threadIdx.x & 63, wv = threadIdx.x >> 6;
    int x = v;
#pragma unroll
    for (int o = 1; o < 64; o <<= 1) {
        int y = __shfl_up(x, o);
        if (lane >= o) x += y;
    }
    __shared__ int ws[4];
    if (lane == 63) ws[wv] = x;
    __syncthreads();
    int wo = 0;
#pragma unroll
    for (int w = 0; w < 4; ++w) if (w < wv) wo += ws[w];
    if (i < NN) {
        int r = bofs[blockIdx.x] + x + wo - v;   // exclusive global
        rowp[i] = r; cur[i] = r;
    }
}

__global__ __launch_bounds__(256) void scatter_kernel(
    const int* __restrict__ ei, int* __restrict__ cur, int* __restrict__ esrc)
{
    const int xcd  = blockIdx.x & (NXCD - 1);
    const int slot = blockIdx.x >> 3;
    const int lo = xcd * NPX, hi = lo + NPX;
    const int base = slot * EDGES_PER_SLOT;
#pragma unroll
    for (int it = 0; it < EDGES_PER_SLOT / 256; ++it) {
        int e = base + it * 256 + threadIdx.x;
        if (e < ETOT) {
            int s, d;
            if (e < EE) { s = ei[e]; d = ei[EE + e]; }
            else        { s = e - EE; d = s; }
            if (d >= lo && d < hi) {
                int pos = atomicAdd(&cur[d], 1);
                esrc[pos] = s;
            }
        }
    }
}

// ================= W -> bf16 MFMA fragment order =================
__global__ __launch_bounds__(256) void wfrag_kernel(
    const float* __restrict__ W, unsigned short* __restrict__ Wf, int K)
{
    int t = blockIdx.x * 256 + threadIdx.x;       // t = frag*64 + lane
    if (t >= K * 16) return;                      // (K/32)*8*64 == K*16
    int lane = t & 63, frag = t >> 6;
    int kblk = frag >> 3, nt = frag & 7;
    int quad = lane >> 4, ln = lane & 15;
    int kbase = kblk * 32 + quad * 8;
    int n = nt * 16 + ln;
    unsigned short u[8];
#pragma unroll
    for (int j = 0; j < 8; ++j)
        u[j] = (unsigned short)f2bf(W[(size_t)(kbase + j) * HC + n]);
    ushort4 a; a.x = u[0]; a.y = u[1]; a.z = u[2]; a.w = u[3];
    ushort4 b; b.x = u[4]; b.y = u[5]; b.z = u[6]; b.w = u[7];
    *(ushort4*)(Wf + (size_t)t * 8)     = a;
    *(ushort4*)(Wf + (size_t)t * 8 + 4) = b;
}

// ================= barrier-free per-wave MFMA GEMM, column-split =================
// Grid = 2 * ceil(N/64): block handles 64 rows x 64 cols (one head). Each wave:
// 16 rows x 64 cols, 4 accs. Column split doubles wave count (6256 waves, ~24/CU)
// and halves per-wave registers -> latency hidden by TLP instead of a deep pipeline.
// hb packing: uint at [m*64 + half*32 + t*16 + ln] = bf16 pair (col c, col c+16),
// c = half*64 + t*32 + ln  => consumer decode c_lo = j + (j & 48).
template<int K, bool AFFINE>
__global__ __launch_bounds__(256) void mfma_gemm_kernel(
    const float* __restrict__ A, const unsigned short* __restrict__ Wf,
    const float* __restrict__ atts, const float* __restrict__ attd,
    unsigned* __restrict__ hb, float* __restrict__ as_, float* __restrict__ ad_,
    const float* __restrict__ sc, const float* __restrict__ sh)
{
    constexpr int NSTEP = K >> 5;
    constexpr int AD = (NSTEP < 4) ? NSTEP : 4;   // A-prefetch depth

    const int tid  = threadIdx.x;
    const int wave = tid >> 6, lane = tid & 63;
    const int quad = lane >> 4, ln = lane & 15;
    const int tilei = blockIdx.x >> 1;
    const int half  = blockIdx.x & 1;             // which head / col-half
    const int m0 = tilei * 64;
    const int myrow = m0 + wave * 16 + ln;
    const bool rok = (myrow < NN);
    const float* arow = A + (size_t)(rok ? myrow : 0) * K + quad * 8;
    const unsigned short* wbase = Wf + (size_t)(half * 4) * 512 + lane * 8;

    f32x4 acc[4];
#pragma unroll
    for (int nt = 0; nt < 4; ++nt) acc[nt] = (f32x4){0.f, 0.f, 0.f, 0.f};

    // prologue: A-prefetch pipeline, AD steps deep
    const float4 z4 = make_float4(0.f, 0.f, 0.f, 0.f);
    float4 pa[AD], pb[AD];
#pragma unroll
    for (int d = 0; d < AD; ++d) {
        if (rok) {
            pa[d] = *(const float4*)(arow + d * 32);
            pb[d] = *(const float4*)(arow + d * 32 + 4);
        } else { pa[d] = z4; pb[d] = z4; }
    }

    // B double buffer: step 0
    bf16x8 bfr[2][4];
#pragma unroll
    for (int nt = 0; nt < 4; ++nt) bfr[0][nt] = *(const bf16x8*)(wbase + nt * 512);

#pragma unroll
    for (int ks = 0; ks < NSTEP; ++ks) {
        const int cur = ks & 1;
        if (ks + 1 < NSTEP) {
            const unsigned short* wfp = wbase + (size_t)(ks + 1) * 4096;
#pragma unroll
            for (int nt = 0; nt < 4; ++nt)
                bfr[cur ^ 1][nt] = *(const bf16x8*)(wfp + nt * 512);
        }

        float4 ca = pa[ks % AD], cb = pb[ks % AD];
        float va[8] = {ca.x, ca.y, ca.z, ca.w, cb.x, cb.y, cb.z, cb.w};
        if (AFFINE) {
            const int kk = ks * 32 + quad * 8;
            const float4 s0 = *(const float4*)(sc + kk), s1 = *(const float4*)(sc + kk + 4);
            const float4 h0 = *(const float4*)(sh + kk), h1 = *(const float4*)(sh + kk + 4);
            va[0] = fmaxf(fmaf(s0.x, va[0], h0.x), 0.f);
            va[1] = fmaxf(fmaf(s0.y, va[1], h0.y), 0.f);
            va[2] = fmaxf(fmaf(s0.z, va[2], h0.z), 0.f);
            va[3] = fmaxf(fmaf(s0.w, va[3], h0.w), 0.f);
            va[4] = fmaxf(fmaf(s1.x, va[4], h1.x), 0.f);
            va[5] = fmaxf(fmaf(s1.y, va[5], h1.y), 0.f);
            va[6] = fmaxf(fmaf(s1.z, va[6], h1.z), 0.f);
            va[7] = fmaxf(fmaf(s1.w, va[7], h1.w), 0.f);
        }
        union { bf16x8 v; unsigned short u[8]; } af;
#pragma unroll
        for (int j = 0; j < 8; ++j) af.u[j] = (unsigned short)f2bf(va[j]);

        if (ks + AD < NSTEP && rok) {
            const float* nx = arow + (size_t)(ks + AD) * 32;
            pa[ks % AD] = *(const float4*)nx;
            pb[ks % AD] = *(const float4*)(nx + 4);
        }

#pragma unroll
        for (int nt = 0; nt < 4; ++nt)
            acc[nt] = __builtin_amdgcn_mfma_f32_16x16x32_bf16(af.v, bfr[cur][nt], acc[nt], 0, 0, 0);
    }

    // epilogue; C/D layout col=ln, row=quad*4+r. This block's cols = half*64 + nt*16 + ln.
    float wsv[4], wdv[4];
#pragma unroll
    for (int nt = 0; nt < 4; ++nt) {
        wsv[nt] = atts[(half * 4 + nt) * 16 + ln];
        wdv[nt] = attd[(half * 4 + nt) * 16 + ln];
    }

    const int mbase = m0 + wave * 16 + quad * 4;
#pragma unroll
    for (int r = 0; r < 4; ++r) {
        int m = mbase + r;
        bool ok = (m < NN);
        float ps = 0.f, pd = 0.f;
#pragma unroll
        for (int nt = 0; nt < 4; ++nt) {
            float v = acc[nt][r];
            ps = fmaf(v, wsv[nt], ps);
            pd = fmaf(v, wdv[nt], pd);
        }
        // pack (col c, col c+16): (acc0,acc1) and (acc2,acc3)
        unsigned u0 = f2bf(acc[0][r]) | (f2bf(acc[1][r]) << 16);
        unsigned u1 = f2bf(acc[2][r]) | (f2bf(acc[3][r]) << 16);
        if (ok) {
            hb[(size_t)m * 64 + half * 32 + ln]      = u0;
            hb[(size_t)m * 64 + half * 32 + 16 + ln] = u1;
        }
#pragma unroll
        for (int o = 8; o > 0; o >>= 1) {
            ps += __shfl_down(ps, o);
            pd += __shfl_down(pd, o);
        }
        if (ok && ln == 0) {
            as_[m * 2 + half] = ps;
            ad_[m * 2 + half] = pd;
        }
    }
}

// ================= fused segment-softmax + aggregate: one wave per dst node =================
// hb uint j of a node: bf16 pair (col c_lo, col c_lo+16), c_lo = j + (j & 48); head = j>>5.
__global__ __launch_bounds__(256) void gat_agg_kernel(
    const int* __restrict__ rowp, const int* __restrict__ esrc,
    const float* __restrict__ as_, const float* __restrict__ ad_,
    const unsigned* __restrict__ hb, float* __restrict__ out)
{
    int node = (blockIdx.x * 256 + threadIdx.x) >> 6;
    int lane = threadIdx.x & 63;
    if (node >= NN) return;
    int beg = rowp[node], end = rowp[node + 1];
    float2 adv = *(const float2*)&ad_[node * 2];
    const bool h1 = (lane >= 32);
    const int c_lo = lane + (lane & 48);

    float l0 = 0.f, l1 = 0.f, a_lo = 0.f, a_hi = 0.f;

    for (int j0 = beg; j0 < end; j0 += 64) {
        int nj = min(64, end - j0);
        int   sl  = 0;
        float p0l = 0.f, p1l = 0.f;
        if (j0 + lane < end) {
            sl = esrc[j0 + lane];
            float2 t = *(const float2*)&as_[sl * 2];
            float e0 = t.x + adv.x; e0 = fmaxf(e0, NEG_SLOPE * e0);
            float e1 = t.y + adv.y; e1 = fmaxf(e1, NEG_SLOPE * e1);
            p0l = __expf(e0); p1l = __expf(e1);
        }
        l0 += p0l; l1 += p1l;          // per-lane partial denominator

        int j = 0;
        for (; j + 2 <= nj; j += 2) {
            int sA = __shfl(sl, j), sB = __shfl(sl, j + 1);
            unsigned uA = hb[(size_t)sA * 64 + lane];
            unsigned uB = hb[(size_t)sB * 64 + lane];
            float pA0 = __shfl(p0l, j),     pA1 = __shfl(p1l, j);
            float pB0 = __shfl(p0l, j + 1), pB1 = __shfl(p1l, j + 1);
            float pA = h1 ? pA1 : pA0;
            float pB = h1 ? pB1 : pB0;
            a_lo = fmaf(pA, __uint_as_float(uA << 16), a_lo);
            a_hi = fmaf(pA, __uint_as_float(uA & 0xffff0000u), a_hi);
            a_lo = fmaf(pB, __uint_as_float(uB << 16), a_lo);
            a_hi = fmaf(pB, __uint_as_float(uB & 0xffff0000u), a_hi);
        }
        if (j < nj) {
            int s = __shfl(sl, j);
            unsigned u = hb[(size_t)s * 64 + lane];
            float p0 = __shfl(p0l, j), p1 = __shfl(p1l, j);
            float p = h1 ? p1 : p0;
            a_lo = fmaf(p, __uint_as_float(u << 16), a_lo);
            a_hi = fmaf(p, __uint_as_float(u & 0xffff0000u), a_hi);
        }
    }

#pragma unroll
    for (int o = 1; o < 64; o <<= 1) {
        l0 += __shfl_xor(l0, o); l1 += __shfl_xor(l1, o);
    }
    float rl = 1.f / (h1 ? l1 : l0);
    out[(size_t)node * HC + c_lo]      = a_lo * rl;
    out[(size_t)node * HC + c_lo + 16] = a_hi * rl;
}

// ================= BN stats =================
__global__ __launch_bounds__(256) void bn_stats_kernel(
    const float* __restrict__ x, float* __restrict__ stats)
{
    int c = threadIdx.x & 127;
    int half = threadIdx.x >> 7;
    float s = 0.f, sq = 0.f;
    for (int r = blockIdx.x * 2 + half; r < NN; r += gridDim.x * 2) {
        float v = x[(size_t)r * HC + c];
        s += v; sq += v * v;
    }
    __shared__ float ls[256], lq[256];
    ls[threadIdx.x] = s; lq[threadIdx.x] = sq;
    __syncthreads();
    if (half == 0) {
        s += ls[threadIdx.x + 128];
        sq += lq[threadIdx.x + 128];
        atomicAdd(&stats[c], s);
        atomicAdd(&stats[128 + c], sq);
    }
}

__global__ void bn_params_kernel(
    const float* __restrict__ stats, const float* __restrict__ gamma,
    const float* __restrict__ beta, float* __restrict__ sc, float* __restrict__ sh)
{
    int c = threadIdx.x;
    const float inv_n = 1.0f / (float)NN;
    float mu = stats[c] * inv_n;
    float var = stats[128 + c] * inv_n - mu * mu;
    float rs = rsqrtf(var + BN_EPS);
    float s = gamma[c] * rs;
    sc[c] = s;
    sh[c] = beta[c] - mu * s;
}

// ================= pool: 64 rows/block (782 blocks), flush-on-graph-change =================
__global__ __launch_bounds__(256) void pool_kernel(
    const float* __restrict__ x, const float* __restrict__ sc,
    const float* __restrict__ sh, const int* __restrict__ batch,
    float* __restrict__ pool, float* __restrict__ cnt)
{
    int c = threadIdx.x & 127;
    int half = threadIdx.x >> 7;
    int r0 = blockIdx.x * 64;
    int rend = min(r0 + 64, NN);
    float s = sc[c], b = sh[c];
    int cur = -1; float acc = 0.f, ccount = 0.f;
    for (int r = r0 + half; r < rend; r += 2) {
        int g = batch[r];
        if (g != cur) {
            if (cur >= 0) {
                atomicAdd(&pool[cur * HC + c], acc);
                if (c == 0) atomicAdd(&cnt[cur], ccount);
            }
            cur = g; acc = 0.f; ccount = 0.f;
        }
        float v = x[(size_t)r * HC + c];
        acc += fmaxf(fmaf(s, v, b), 0.f);
        ccount += 1.f;
    }
    if (cur >= 0) {
        atomicAdd(&pool[cur * HC + c], acc);
        if (c == 0) atomicAdd(&cnt[cur], ccount);
    }
}

// ================= final linear: [64,128]@[128,2] + blin =================
__global__ void final_kernel(
    const float* __restrict__ pool, const float* __restrict__ cnt,
    const float* __restrict__ Wlin, const float* __restrict__ blin,
    float* __restrict__ outp)
{
    int t = threadIdx.x;               // 128 threads
    int b = t >> 1, oc = t & 1;
    float inv = 1.f / fmaxf(cnt[b], 1.f);
    float s = blin[oc];
    for (int c = 0; c < HC; ++c)
        s += pool[b * HC + c] * inv * Wlin[c * 2 + oc];
    outp[b * 2 + oc] = s;
}

// ================= workspace layout =================
// floats
static constexpr size_t OFF_OUT   = 0;                        // [N*HC]
static constexpr size_t OFF_AS    = OFF_OUT + (size_t)NN*HC;  // [N*2]
static constexpr size_t OFF_AD    = OFF_AS  + (size_t)NN*HH;
static constexpr size_t OFF_ST1   = OFF_AD  + (size_t)NN*HH;  // zero from here: [256]
static constexpr size_t OFF_ST2   = OFF_ST1 + 256;
static constexpr size_t OFF_SC1   = OFF_ST2 + 256;            // [128]
static constexpr size_t OFF_SH1   = OFF_SC1 + 128;
static constexpr size_t OFF_SC2   = OFF_SH1 + 128;
static constexpr size_t OFF_SH2   = OFF_SC2 + 128;
static constexpr size_t OFF_POOL  = OFF_SH2 + 128;            // [B*HC]
static constexpr size_t OFF_CNT   = OFF_POOL+ (size_t)BB*HC;  // [B]
static constexpr size_t OFF_ZEND  = OFF_CNT + BB;             // end of zeroed float region
// ints (after float region)
static constexpr size_t IOFF_DEG  = 0;                        // [N]  (zeroed)
static constexpr size_t IOFF_ROWP = IOFF_DEG  + NN;           // [N+1]
static constexpr size_t IOFF_CUR  = IOFF_ROWP + NN + 1;       // [N]
static constexpr size_t IOFF_BSUM = IOFF_CUR  + NN;           // [NBLK_SCAN]
static constexpr size_t IOFF_BOFS = IOFF_BSUM + NBLK_SCAN;    // [NBLK_SCAN]
static constexpr size_t IOFF_ESRC = IOFF_BOFS + NBLK_SCAN;    // [ETOT]
static constexpr size_t IOFF_HB   = (IOFF_ESRC + ETOT + 3) & ~(size_t)3;  // [N*64] uints
static constexpr size_t IOFF_WF1  = IOFF_HB + (size_t)NN*64;  // [512*64] ints
static constexpr size_t IOFF_WF2  = IOFF_WF1 + (size_t)IN_C*64; // [128*64] ints
static constexpr size_t IOFF_END  = IOFF_WF2 + (size_t)HC*64;

extern "C" void kernel_launch(void* const* d_in, const int* in_sizes, int n_in,
                              void* d_out, int out_size, void* d_ws, size_t ws_size,
                              hipStream_t stream)
{
    const float* x       = (const float*)d_in[0];
    const int*   ei      = (const int*)  d_in[1];
    const int*   batch   = (const int*)  d_in[2];
    const float* W1      = (const float*)d_in[3];
    const float* atts1   = (const float*)d_in[4];
    const float* attd1   = (const float*)d_in[5];
    const float* gamma1  = (const float*)d_in[7];
    const float* beta1   = (const float*)d_in[8];
    const float* W2      = (const float*)d_in[9];
    const float* atts2   = (const float*)d_in[10];
    const float* attd2   = (const float*)d_in[11];
    const float* gamma2  = (const float*)d_in[13];
    const float* beta2   = (const float*)d_in[14];
    const float* Wlin    = (const float*)d_in[15];
    const float* blin    = (const float*)d_in[16];
    float* outp = (float*)d_out;

    float* ws    = (float*)d_ws;
    float* out   = ws + OFF_OUT;
    float* as_   = ws + OFF_AS;
    float* ad_   = ws + OFF_AD;
    float* st1   = ws + OFF_ST1;
    float* st2   = ws + OFF_ST2;
    float* sc1   = ws + OFF_SC1;
    float* sh1   = ws + OFF_SH1;
    float* sc2   = ws + OFF_SC2;
    float* sh2   = ws + OFF_SH2;
    float* pool  = ws + OFF_POOL;
    float* cnt   = ws + OFF_CNT;

    int* iws  = (int*)(ws + OFF_ZEND);
    int* deg  = iws + IOFF_DEG;
    int* rowp = iws + IOFF_ROWP;
    int* curp = iws + IOFF_CUR;
    int* bsum = iws + IOFF_BSUM;
    int* bofs = iws + IOFF_BOFS;
    int* esrc = iws + IOFF_ESRC;
    unsigned* hb = (unsigned*)(iws + IOFF_HB);
    unsigned short* Wf1 = (unsigned short*)(iws + IOFF_WF1);
    unsigned short* Wf2 = (unsigned short*)(iws + IOFF_WF2);

    const int BIN_BLK   = NXCD * NSLOT;          // 8 * 416 = 3328
    const int GEMM_BLK  = 2 * ((NN + 63) / 64);  // 1564: col-split, 64 rows x 64 cols
    const int WAVE_BLK  = (NN + 3) / 4;          // 1 wave per node, 4 waves/block
    const int POOL_BLK  = (NN + 63) / 64;        // 782: 64 rows/block

    // zero: bn-stats/pool/cnt float region + deg
    hipMemsetAsync(st1, 0, (OFF_ZEND - OFF_ST1) * sizeof(float), stream);
    hipMemsetAsync(deg, 0, NN * sizeof(int), stream);

    // ----- weight fragment packs + CSR build (shared by both layers) -----
    wfrag_kernel<<<(IN_C * 16 + 255) / 256, 256, 0, stream>>>(W1, Wf1, IN_C);
    wfrag_kernel<<<(HC   * 16 + 255) / 256, 256, 0, stream>>>(W2, Wf2, HC);
    deg_kernel<<<BIN_BLK, 256, 0, stream>>>(ei, deg);
    bsum_kernel<<<NBLK_SCAN, 256, 0, stream>>>(deg, bsum);
    bscan_kernel<<<1, 256, 0, stream>>>(bsum, bofs, rowp);
    bapply_kernel<<<NBLK_SCAN, 256, 0, stream>>>(deg, bofs, rowp, curp);
    scatter_kernel<<<BIN_BLK, 256, 0, stream>>>(ei, curp, esrc);

    // ----- layer 1 (GEMM + fused alpha + bf16 pack) -----
    mfma_gemm_kernel<IN_C, false><<<GEMM_BLK, 256, 0, stream>>>(
        x, Wf1, atts1, attd1, hb, as_, ad_, nullptr, nullptr);
    gat_agg_kernel<<<WAVE_BLK, 256, 0, stream>>>(rowp, esrc, as_, ad_, hb, out);
    bn_stats_kernel<<<512, 256, 0, stream>>>(out, st1);
    bn_params_kernel<<<1, 128, 0, stream>>>(st1, gamma1, beta1, sc1, sh1);

    // ----- layer 2 (BN1-affine+ReLU fused into GEMM2 A-load) -----
    mfma_gemm_kernel<HC, true><<<GEMM_BLK, 256, 0, stream>>>(
        out, Wf2, atts2, attd2, hb, as_, ad_, sc1, sh1);
    gat_agg_kernel<<<WAVE_BLK, 256, 0, stream>>>(rowp, esrc, as_, ad_, hb, out);
    bn_stats_kernel<<<512, 256, 0, stream>>>(out, st2);
    bn_params_kernel<<<1, 128, 0, stream>>>(st2, gamma2, beta2, sc2, sh2);

    // ----- pool + final linear -----
    pool_kernel<<<POOL_BLK, 256, 0, stream>>>(out, sc2, sh2, batch, pool, cnt);
    final_kernel<<<1, 128, 0, stream>>>(pool, cnt, Wlin, blin, outp);
}

// Round 3
// 469.091 us; speedup vs baseline: 1.1096x; 1.0391x over previous
//
#include <hip/hip_runtime.h>
#include <hip/hip_bf16.h>
#include <cstdint>
#include <cstddef>

// Problem constants (match reference)
#define NN      50000
#define IN_C    512
#define EE      800000
#define ETOT    850000      // E + N self-loops
#define HH      2
#define CC      64
#define HC      128
#define BB      64
#define OUTC    2
#define NEG_SLOPE 0.2f
#define BN_EPS  1e-5f

#define NBLK_SCAN ((NN + 255) / 256)   // 196

// XCD binning for CSR build: 8 dst ranges, blockIdx%8 -> XCD (round-robin dispatch)
#define NXCD     8
#define NPX      ((NN + NXCD - 1) / NXCD)        // 6250 nodes per bin
#define EDGES_PER_SLOT 2048
#define NSLOT    ((ETOT + EDGES_PER_SLOT - 1) / EDGES_PER_SLOT)  // 416

typedef __bf16 bf16x8 __attribute__((ext_vector_type(8)));
typedef float  f32x4  __attribute__((ext_vector_type(4)));

__device__ __forceinline__ unsigned f2bf(float f) {
    __bf16 b = (__bf16)f;                      // RNE convert
    return (unsigned)__builtin_bit_cast(unsigned short, b);
}

// async global->LDS, 16B per lane; LDS dest is wave-uniform base + lane*16
__device__ __forceinline__ void gload_lds16(const float* g, float* l) {
    __builtin_amdgcn_global_load_lds(
        (const __attribute__((address_space(1))) unsigned*)g,
        (__attribute__((address_space(3))) unsigned*)l,
        16, 0, 0);
}

// ================= CSR build (XCD-binned: each XCD owns a dst range; atomics and
// esrc writes stay in one L2 — no cross-XCD line ping-pong / write amplification) ==========
__global__ __launch_bounds__(256) void deg_kernel(const int* __restrict__ ei, int* __restrict__ deg)
{
    const int xcd  = blockIdx.x & (NXCD - 1);
    const int slot = blockIdx.x >> 3;
    const int lo = xcd * NPX, hi = lo + NPX;
    const int base = slot * EDGES_PER_SLOT;
#pragma unroll
    for (int it = 0; it < EDGES_PER_SLOT / 256; ++it) {
        int e = base + it * 256 + threadIdx.x;
        if (e < ETOT) {
            int d = (e < EE) ? ei[EE + e] : (e - EE);
            if (d >= lo && d < hi) atomicAdd(&deg[d], 1);
        }
    }
}

// --- hierarchical scan ---
__global__ __launch_bounds__(256) void bsum_kernel(const int* __restrict__ deg, int* __restrict__ bsum)
{
    int i = blockIdx.x * 256 + threadIdx.x;
    int v = (i < NN) ? deg[i] : 0;
    int lane = threadIdx.x & 63, wv = threadIdx.x >> 6;
#pragma unroll
    for (int o = 32; o > 0; o >>= 1) v += __shfl_down(v, o);
    __shared__ int ws[4];
    if (lane == 0) ws[wv] = v;
    __syncthreads();
    if (threadIdx.x == 0) bsum[blockIdx.x] = ws[0] + ws[1] + ws[2] + ws[3];
}

__global__ __launch_bounds__(256) void bscan_kernel(
    const int* __restrict__ bsum, int* __restrict__ bofs, int* __restrict__ rowp)
{
    int t = threadIdx.x;
    int lane = t & 63, wv = t >> 6;
    int v = (t < NBLK_SCAN) ? bsum[t] : 0;
    int x = v;
#pragma unroll
    for (int o = 1; o < 64; o <<= 1) {
        int y = __shfl_up(x, o);
        if (lane >= o) x += y;
    }
    __shared__ int ws[4];
    if (lane == 63) ws[wv] = x;
    __syncthreads();
    int wo = 0;
#pragma unroll
    for (int w = 0; w < 4; ++w) if (w < wv) wo += ws[w];
    if (t < NBLK_SCAN) bofs[t] = x + wo - v;     // exclusive
    if (t == 0) rowp[NN] = ETOT;
}

__global__ __launch_bounds__(256) void bapply_kernel(
    const int* __restrict__ deg, const int* __restrict__ bofs,
    int* __restrict__ rowp, int* __restrict__ cur)
{
    int i = blockIdx.x * 256 + threadIdx.x;
    int v = (i < NN) ? deg[i] : 0;
    int lane = threadIdx.x & 63, wv = threadIdx.x >> 6;
    int x = v;
#pragma unroll
    for (int o = 1; o < 64; o <<= 1) {
        int y = __shfl_up(x, o);
        if (lane >= o) x += y;
    }
    __shared__ int ws[4];
    if (lane == 63) ws[wv] = x;
    __syncthreads();
    int wo = 0;
#pragma unroll
    for (int w = 0; w < 4; ++w) if (w < wv) wo += ws[w];
    if (i < NN) {
        int r = bofs[blockIdx.x] + x + wo - v;   // exclusive global
        rowp[i] = r; cur[i] = r;
    }
}

__global__ __launch_bounds__(256) void scatter_kernel(
    const int* __restrict__ ei, int* __restrict__ cur, int* __restrict__ esrc)
{
    const int xcd  = blockIdx.x & (NXCD - 1);
    const int slot = blockIdx.x >> 3;
    const int lo = xcd * NPX, hi = lo + NPX;
    const int base = slot * EDGES_PER_SLOT;
#pragma unroll
    for (int it = 0; it < EDGES_PER_SLOT / 256; ++it) {
        int e = base + it * 256 + threadIdx.x;
        if (e < ETOT) {
            int s, d;
            if (e < EE) { s = ei[e]; d = ei[EE + e]; }
            else        { s = e - EE; d = s; }
            if (d >= lo && d < hi) {
                int pos = atomicAdd(&cur[d], 1);
                esrc[pos] = s;
            }
        }
    }
}

// ================= W -> bf16 MFMA fragment order =================
__global__ __launch_bounds__(256) void wfrag_kernel(
    const float* __restrict__ W, unsigned short* __restrict__ Wf, int K)
{
    int t = blockIdx.x * 256 + threadIdx.x;       // t = frag*64 + lane
    if (t >= K * 16) return;                      // (K/32)*8*64 == K*16
    int lane = t & 63, frag = t >> 6;
    int kblk = frag >> 3, nt = frag & 7;
    int quad = lane >> 4, ln = lane & 15;
    int kbase = kblk * 32 + quad * 8;
    int n = nt * 16 + ln;
    unsigned short u[8];
#pragma unroll
    for (int j = 0; j < 8; ++j)
        u[j] = (unsigned short)f2bf(W[(size_t)(kbase + j) * HC + n]);
    ushort4 a; a.x = u[0]; a.y = u[1]; a.z = u[2]; a.w = u[3];
    ushort4 b; b.x = u[4]; b.y = u[5]; b.z = u[6]; b.w = u[7];
    *(ushort4*)(Wf + (size_t)t * 8)     = a;
    *(ushort4*)(Wf + (size_t)t * 8 + 4) = b;
}

// ================= LDS-staged MFMA GEMM (m97 structure) =================
// Block = 64 rows x 128 cols, 4 waves (each 16 rows x 128 cols, 8 accs).
// A staged into LDS via global_load_lds (coalesced 16B/lane, no VGPR round-trip),
// double-buffered, 1 barrier per K-step. LDS tile [64 rows][8 x 16B slots],
// XOR-swizzled: slot s of row r holds A[r][s ^ (r&7)] (pre-swizzled GLOBAL source,
// linear LDS dest — rule 21). ds_read_b128 at ((q*2+j)^(r&7)) -> <=2-way conflict.
// B streamed from L2 into regs, double-buffered (128KB, L2-hot).
template<int K, bool AFFINE>
__global__ __launch_bounds__(256) void mfma_gemm_kernel(
    const float* __restrict__ A, const unsigned short* __restrict__ Wf,
    const float* __restrict__ atts, const float* __restrict__ attd,
    unsigned* __restrict__ hb, float* __restrict__ as_, float* __restrict__ ad_,
    const float* __restrict__ sc, const float* __restrict__ sh)
{
    constexpr int NSTEP = K >> 5;
    __shared__ __align__(16) float Abuf[2][64 * 32];   // 2 x 8 KB

    const int tid  = threadIdx.x;
    const int wave = tid >> 6, lane = tid & 63;
    const int quad = lane >> 4, ln = lane & 15;
    const int m0 = blockIdx.x * 64;

    // ---- staging geometry: thread t covers 16B slot t (row t>>3, slot t&7), rows +0/+32
    const int srow = tid >> 3;                 // 0..31
    const int g    = (tid & 7) ^ (srow & 7);   // swizzled source slot ((r+32)&7 == r&7)
    int grow0 = m0 + srow;      if (grow0 > NN - 1) grow0 = NN - 1;
    int grow1 = m0 + srow + 32; if (grow1 > NN - 1) grow1 = NN - 1;
    const float* gsrc0 = A + (size_t)grow0 * K + g * 4;
    const float* gsrc1 = A + (size_t)grow1 * K + g * 4;
    float* ldst0 = &Abuf[0][wave * 256];          // wave-uniform bases
    float* ldst1 = &Abuf[0][1024 + wave * 256];
    const int bufstride = 64 * 32;

    // ---- fragment-read geometry
    const int rr = wave * 16 + ln;             // tile row this lane's A-frag is from
    const int myrow = m0 + rr;
    const int base_f = rr * 32;
    const int sA = (((quad * 2)     ^ (rr & 7)) * 4);
    const int sB = (((quad * 2 + 1) ^ (rr & 7)) * 4);

    const unsigned short* wbase = Wf + lane * 8;

    f32x4 acc[8];
#pragma unroll
    for (int nt = 0; nt < 8; ++nt) acc[nt] = (f32x4){0.f, 0.f, 0.f, 0.f};

    // prologue: stage ks=0, load B step 0
    gload_lds16(gsrc0, ldst0);
    gload_lds16(gsrc1, ldst1);
    bf16x8 bfr[2][8];
#pragma unroll
    for (int nt = 0; nt < 8; ++nt) bfr[0][nt] = *(const bf16x8*)(wbase + nt * 512);

#pragma unroll
    for (int ks = 0; ks < NSTEP; ++ks) {
        const int cur = ks & 1;
        // barrier: (a) all waves' stage(cur) loads drained (compiler emits vmcnt(0));
        //          (b) all waves done reading buf[cur^1] -> safe to overwrite
        __syncthreads();
        if (ks + 1 < NSTEP) {
            gload_lds16(gsrc0 + (size_t)(ks + 1) * 32, ldst0 + (cur ^ 1) * bufstride);
            gload_lds16(gsrc1 + (size_t)(ks + 1) * 32, ldst1 + (cur ^ 1) * bufstride);
        }

        float4 fa = *(const float4*)&Abuf[cur][base_f + sA];
        float4 fb = *(const float4*)&Abuf[cur][base_f + sB];
        float va[8] = {fa.x, fa.y, fa.z, fa.w, fb.x, fb.y, fb.z, fb.w};
        if (AFFINE) {
            const int kk = ks * 32 + quad * 8;
            const float4 s0 = *(const float4*)(sc + kk), s1 = *(const float4*)(sc + kk + 4);
            const float4 h0 = *(const float4*)(sh + kk), h1 = *(const float4*)(sh + kk + 4);
            va[0] = fmaxf(fmaf(s0.x, va[0], h0.x), 0.f);
            va[1] = fmaxf(fmaf(s0.y, va[1], h0.y), 0.f);
            va[2] = fmaxf(fmaf(s0.z, va[2], h0.z), 0.f);
            va[3] = fmaxf(fmaf(s0.w, va[3], h0.w), 0.f);
            va[4] = fmaxf(fmaf(s1.x, va[4], h1.x), 0.f);
            va[5] = fmaxf(fmaf(s1.y, va[5], h1.y), 0.f);
            va[6] = fmaxf(fmaf(s1.z, va[6], h1.z), 0.f);
            va[7] = fmaxf(fmaf(s1.w, va[7], h1.w), 0.f);
        }
        union { bf16x8 v; unsigned short u[8]; } af;
#pragma unroll
        for (int j = 0; j < 8; ++j) af.u[j] = (unsigned short)f2bf(va[j]);

        // prefetch next step's B-frags (L2-hot; in flight across this step's MFMAs)
        if (ks + 1 < NSTEP) {
            const unsigned short* wfp = wbase + (size_t)(ks + 1) * 4096;
#pragma unroll
            for (int nt = 0; nt < 8; ++nt)
                bfr[cur ^ 1][nt] = *(const bf16x8*)(wfp + nt * 512);
        }

#pragma unroll
        for (int nt = 0; nt < 8; ++nt)
            acc[nt] = __builtin_amdgcn_mfma_f32_16x16x32_bf16(af.v, bfr[cur][nt], acc[nt], 0, 0, 0);
    }

    // epilogue: pack bf16 pairs + fused attention logits; C/D layout col=ln, row=quad*4+r
    float wsv[8], wdv[8];
#pragma unroll
    for (int nt = 0; nt < 8; ++nt) { wsv[nt] = atts[nt * 16 + ln]; wdv[nt] = attd[nt * 16 + ln]; }

    const int mbase = m0 + wave * 16 + quad * 4;
#pragma unroll
    for (int r = 0; r < 4; ++r) {
        int m = mbase + r;
        bool ok = (m < NN);
        float ps0 = 0.f, ps1 = 0.f, pd0 = 0.f, pd1 = 0.f;
#pragma unroll
        for (int nt = 0; nt < 8; ++nt) {
            float v = acc[nt][r];
            if (nt < 4) { ps0 = fmaf(v, wsv[nt], ps0); pd0 = fmaf(v, wdv[nt], pd0); }
            else        { ps1 = fmaf(v, wsv[nt], ps1); pd1 = fmaf(v, wdv[nt], pd1); }
        }
#pragma unroll
        for (int nt = 0; nt < 4; ++nt) {
            unsigned pk = f2bf(acc[nt][r]) | (f2bf(acc[nt + 4][r]) << 16);
            if (ok) hb[(size_t)m * 64 + nt * 16 + ln] = pk;
        }
#pragma unroll
        for (int o = 8; o > 0; o >>= 1) {
            ps0 += __shfl_down(ps0, o); ps1 += __shfl_down(ps1, o);
            pd0 += __shfl_down(pd0, o); pd1 += __shfl_down(pd1, o);
        }
        if (ok && ln == 0) {
            *(float2*)&as_[m * 2] = make_float2(ps0, ps1);
            *(float2*)&ad_[m * 2] = make_float2(pd0, pd1);
        }
    }
}

// ================= fused segment-softmax + aggregate: one wave per dst node =================
// Per-lane exp/leaky computed vectorized; serial broadcast loop = shfl + gather + 2 FMA,
// unrolled 4 edges/iter for gather MLP. Denominator via butterfly at the end.
__global__ __launch_bounds__(256) void gat_agg_kernel(
    const int* __restrict__ rowp, const int* __restrict__ esrc,
    const float* __restrict__ as_, const float* __restrict__ ad_,
    const unsigned* __restrict__ hb, float* __restrict__ out)
{
    int node = (blockIdx.x * 256 + threadIdx.x) >> 6;
    int lane = threadIdx.x & 63;
    if (node >= NN) return;
    int beg = rowp[node], end = rowp[node + 1];
    float2 adv = *(const float2*)&ad_[node * 2];

    float l0 = 0.f, l1 = 0.f, a0 = 0.f, a1 = 0.f;

    for (int j0 = beg; j0 < end; j0 += 64) {
        int nj = min(64, end - j0);
        int   sl  = 0;
        float p0l = 0.f, p1l = 0.f;
        if (j0 + lane < end) {
            sl = esrc[j0 + lane];
            float2 t = *(const float2*)&as_[sl * 2];
            float e0 = t.x + adv.x; e0 = fmaxf(e0, NEG_SLOPE * e0);
            float e1 = t.y + adv.y; e1 = fmaxf(e1, NEG_SLOPE * e1);
            p0l = __expf(e0); p1l = __expf(e1);
        }
        l0 += p0l; l1 += p1l;          // per-lane partial denominator

        int j = 0;
        for (; j + 4 <= nj; j += 4) {
            int sA = __shfl(sl, j),     sB = __shfl(sl, j + 1);
            int sC = __shfl(sl, j + 2), sD = __shfl(sl, j + 3);
            unsigned uA = hb[(size_t)sA * 64 + lane];
            unsigned uB = hb[(size_t)sB * 64 + lane];
            unsigned uC = hb[(size_t)sC * 64 + lane];
            unsigned uD = hb[(size_t)sD * 64 + lane];
            float pA0 = __shfl(p0l, j),     pA1 = __shfl(p1l, j);
            float pB0 = __shfl(p0l, j + 1), pB1 = __shfl(p1l, j + 1);
            float pC0 = __shfl(p0l, j + 2), pC1 = __shfl(p1l, j + 2);
            float pD0 = __shfl(p0l, j + 3), pD1 = __shfl(p1l, j + 3);
            a0 = fmaf(pA0, __uint_as_float(uA << 16), a0);
            a1 = fmaf(pA1, __uint_as_float(uA & 0xffff0000u), a1);
            a0 = fmaf(pB0, __uint_as_float(uB << 16), a0);
            a1 = fmaf(pB1, __uint_as_float(uB & 0xffff0000u), a1);
            a0 = fmaf(pC0, __uint_as_float(uC << 16), a0);
            a1 = fmaf(pC1, __uint_as_float(uC & 0xffff0000u), a1);
            a0 = fmaf(pD0, __uint_as_float(uD << 16), a0);
            a1 = fmaf(pD1, __uint_as_float(uD & 0xffff0000u), a1);
        }
        for (; j < nj; ++j) {
            int s = __shfl(sl, j);
            unsigned u = hb[(size_t)s * 64 + lane];
            float p0 = __shfl(p0l, j), p1 = __shfl(p1l, j);
            a0 = fmaf(p0, __uint_as_float(u << 16), a0);
            a1 = fmaf(p1, __uint_as_float(u & 0xffff0000u), a1);
        }
    }

#pragma unroll
    for (int o = 1; o < 64; o <<= 1) {
        l0 += __shfl_xor(l0, o); l1 += __shfl_xor(l1, o);
    }
    out[(size_t)node * HC + lane]      = a0 / l0;
    out[(size_t)node * HC + 64 + lane] = a1 / l1;
}

// ================= BN stats =================
__global__ __launch_bounds__(256) void bn_stats_kernel(
    const float* __restrict__ x, float* __restrict__ stats)
{
    int c = threadIdx.x & 127;
    int half = threadIdx.x >> 7;
    float s = 0.f, sq = 0.f;
    for (int r = blockIdx.x * 2 + half; r < NN; r += gridDim.x * 2) {
        float v = x[(size_t)r * HC + c];
        s += v; sq += v * v;
    }
    __shared__ float ls[256], lq[256];
    ls[threadIdx.x] = s; lq[threadIdx.x] = sq;
    __syncthreads();
    if (half == 0) {
        s += ls[threadIdx.x + 128];
        sq += lq[threadIdx.x + 128];
        atomicAdd(&stats[c], s);
        atomicAdd(&stats[128 + c], sq);
    }
}

__global__ void bn_params_kernel(
    const float* __restrict__ stats, const float* __restrict__ gamma,
    const float* __restrict__ beta, float* __restrict__ sc, float* __restrict__ sh)
{
    int c = threadIdx.x;
    const float inv_n = 1.0f / (float)NN;
    float mu = stats[c] * inv_n;
    float var = stats[128 + c] * inv_n - mu * mu;
    float rs = rsqrtf(var + BN_EPS);
    float s = gamma[c] * rs;
    sc[c] = s;
    sh[c] = beta[c] - mu * s;
}

// ================= pool: 64 rows/block (782 blocks), flush-on-graph-change =================
__global__ __launch_bounds__(256) void pool_kernel(
    const float* __restrict__ x, const float* __restrict__ sc,
    const float* __restrict__ sh, const int* __restrict__ batch,
    float* __restrict__ pool, float* __restrict__ cnt)
{
    int c = threadIdx.x & 127;
    int half = threadIdx.x >> 7;
    int r0 = blockIdx.x * 64;
    int rend = min(r0 + 64, NN);
    float s = sc[c], b = sh[c];
    int cur = -1; float acc = 0.f, ccount = 0.f;
    for (int r = r0 + half; r < rend; r += 2) {
        int g = batch[r];
        if (g != cur) {
            if (cur >= 0) {
                atomicAdd(&pool[cur * HC + c], acc);
                if (c == 0) atomicAdd(&cnt[cur], ccount);
            }
            cur = g; acc = 0.f; ccount = 0.f;
        }
        float v = x[(size_t)r * HC + c];
        acc += fmaxf(fmaf(s, v, b), 0.f);
        ccount += 1.f;
    }
    if (cur >= 0) {
        atomicAdd(&pool[cur * HC + c], acc);
        if (c == 0) atomicAdd(&cnt[cur], ccount);
    }
}

// ================= final linear: [64,128]@[128,2] + blin =================
__global__ void final_kernel(
    const float* __restrict__ pool, const float* __restrict__ cnt,
    const float* __restrict__ Wlin, const float* __restrict__ blin,
    float* __restrict__ outp)
{
    int t = threadIdx.x;               // 128 threads
    int b = t >> 1, oc = t & 1;
    float inv = 1.f / fmaxf(cnt[b], 1.f);
    float s = blin[oc];
    for (int c = 0; c < HC; ++c)
        s += pool[b * HC + c] * inv * Wlin[c * 2 + oc];
    outp[b * 2 + oc] = s;
}

// ================= workspace layout =================
// floats
static constexpr size_t OFF_OUT   = 0;                        // [N*HC]
static constexpr size_t OFF_AS    = OFF_OUT + (size_t)NN*HC;  // [N*2]
static constexpr size_t OFF_AD    = OFF_AS  + (size_t)NN*HH;
static constexpr size_t OFF_ST1   = OFF_AD  + (size_t)NN*HH;  // zero from here: [256]
static constexpr size_t OFF_ST2   = OFF_ST1 + 256;
static constexpr size_t OFF_SC1   = OFF_ST2 + 256;            // [128]
static constexpr size_t OFF_SH1   = OFF_SC1 + 128;
static constexpr size_t OFF_SC2   = OFF_SH1 + 128;
static constexpr size_t OFF_SH2   = OFF_SC2 + 128;
static constexpr size_t OFF_POOL  = OFF_SH2 + 128;            // [B*HC]
static constexpr size_t OFF_CNT   = OFF_POOL+ (size_t)BB*HC;  // [B]
static constexpr size_t OFF_ZEND  = OFF_CNT + BB;             // end of zeroed float region
// ints (after float region)
static constexpr size_t IOFF_DEG  = 0;                        // [N]  (zeroed)
static constexpr size_t IOFF_ROWP = IOFF_DEG  + NN;           // [N+1]
static constexpr size_t IOFF_CUR  = IOFF_ROWP + NN + 1;       // [N]
static constexpr size_t IOFF_BSUM = IOFF_CUR  + NN;           // [NBLK_SCAN]
static constexpr size_t IOFF_BOFS = IOFF_BSUM + NBLK_SCAN;    // [NBLK_SCAN]
static constexpr size_t IOFF_ESRC = IOFF_BOFS + NBLK_SCAN;    // [ETOT]
static constexpr size_t IOFF_HB   = (IOFF_ESRC + ETOT + 3) & ~(size_t)3;  // [N*64] uints
static constexpr size_t IOFF_WF1  = IOFF_HB + (size_t)NN*64;  // [512*64] ints
static constexpr size_t IOFF_WF2  = IOFF_WF1 + (size_t)IN_C*64; // [128*64] ints
static constexpr size_t IOFF_END  = IOFF_WF2 + (size_t)HC*64;

extern "C" void kernel_launch(void* const* d_in, const int* in_sizes, int n_in,
                              void* d_out, int out_size, void* d_ws, size_t ws_size,
                              hipStream_t stream)
{
    const float* x       = (const float*)d_in[0];
    const int*   ei      = (const int*)  d_in[1];
    const int*   batch   = (const int*)  d_in[2];
    const float* W1      = (const float*)d_in[3];
    const float* atts1   = (const float*)d_in[4];
    const float* attd1   = (const float*)d_in[5];
    const float* gamma1  = (const float*)d_in[7];
    const float* beta1   = (const float*)d_in[8];
    const float* W2      = (const float*)d_in[9];
    const float* atts2   = (const float*)d_in[10];
    const float* attd2   = (const float*)d_in[11];
    const float* gamma2  = (const float*)d_in[13];
    const float* beta2   = (const float*)d_in[14];
    const float* Wlin    = (const float*)d_in[15];
    const float* blin    = (const float*)d_in[16];
    float* outp = (float*)d_out;

    float* ws    = (float*)d_ws;
    float* out   = ws + OFF_OUT;
    float* as_   = ws + OFF_AS;
    float* ad_   = ws + OFF_AD;
    float* st1   = ws + OFF_ST1;
    float* st2   = ws + OFF_ST2;
    float* sc1   = ws + OFF_SC1;
    float* sh1   = ws + OFF_SH1;
    float* sc2   = ws + OFF_SC2;
    float* sh2   = ws + OFF_SH2;
    float* pool  = ws + OFF_POOL;
    float* cnt   = ws + OFF_CNT;

    int* iws  = (int*)(ws + OFF_ZEND);
    int* deg  = iws + IOFF_DEG;
    int* rowp = iws + IOFF_ROWP;
    int* curp = iws + IOFF_CUR;
    int* bsum = iws + IOFF_BSUM;
    int* bofs = iws + IOFF_BOFS;
    int* esrc = iws + IOFF_ESRC;
    unsigned* hb = (unsigned*)(iws + IOFF_HB);
    unsigned short* Wf1 = (unsigned short*)(iws + IOFF_WF1);
    unsigned short* Wf2 = (unsigned short*)(iws + IOFF_WF2);

    const int BIN_BLK   = NXCD * NSLOT;          // 8 * 416 = 3328
    const int GEMM_BLK  = (NN + 63) / 64;        // 782: 64 rows x 128 cols
    const int WAVE_BLK  = (NN + 3) / 4;          // 1 wave per node, 4 waves/block
    const int POOL_BLK  = (NN + 63) / 64;        // 782: 64 rows/block

    // zero: bn-stats/pool/cnt float region + deg
    hipMemsetAsync(st1, 0, (OFF_ZEND - OFF_ST1) * sizeof(float), stream);
    hipMemsetAsync(deg, 0, NN * sizeof(int), stream);

    // ----- weight fragment packs + CSR build (shared by both layers) -----
    wfrag_kernel<<<(IN_C * 16 + 255) / 256, 256, 0, stream>>>(W1, Wf1, IN_C);
    wfrag_kernel<<<(HC   * 16 + 255) / 256, 256, 0, stream>>>(W2, Wf2, HC);
    deg_kernel<<<BIN_BLK, 256, 0, stream>>>(ei, deg);
    bsum_kernel<<<NBLK_SCAN, 256, 0, stream>>>(deg, bsum);
    bscan_kernel<<<1, 256, 0, stream>>>(bsum, bofs, rowp);
    bapply_kernel<<<NBLK_SCAN, 256, 0, stream>>>(deg, bofs, rowp, curp);
    scatter_kernel<<<BIN_BLK, 256, 0, stream>>>(ei, curp, esrc);

    // ----- layer 1 (GEMM + fused alpha + bf16 pack) -----
    mfma_gemm_kernel<IN_C, false><<<GEMM_BLK, 256, 0, stream>>>(
        x, Wf1, atts1, attd1, hb, as_, ad_, nullptr, nullptr);
    gat_agg_kernel<<<WAVE_BLK, 256, 0, stream>>>(rowp, esrc, as_, ad_, hb, out);
    bn_stats_kernel<<<512, 256, 0, stream>>>(out, st1);
    bn_params_kernel<<<1, 128, 0, stream>>>(st1, gamma1, beta1, sc1, sh1);

    // ----- layer 2 (BN1-affine+ReLU fused into GEMM2 A-load) -----
    mfma_gemm_kernel<HC, true><<<GEMM_BLK, 256, 0, stream>>>(
        out, Wf2, atts2, attd2, hb, as_, ad_, sc1, sh1);
    gat_agg_kernel<<<WAVE_BLK, 256, 0, stream>>>(rowp, esrc, as_, ad_, hb, out);
    bn_stats_kernel<<<512, 256, 0, stream>>>(out, st2);
    bn_params_kernel<<<1, 128, 0, stream>>>(st2, gamma2, beta2, sc2, sh2);

    // ----- pool + final linear -----
    pool_kernel<<<POOL_BLK, 256, 0, stream>>>(out, sc2, sh2, batch, pool, cnt);
    final_kernel<<<1, 128, 0, stream>>>(pool, cnt, Wlin, blin, outp);
}

// Round 4
// 418.933 us; speedup vs baseline: 1.2425x; 1.1197x over previous
//
#include <hip/hip_runtime.h>
#include <hip/hip_bf16.h>
#include <cstdint>
#include <cstddef>

// Problem constants (match reference)
#define NN      50000
#define IN_C    512
#define EE      800000
#define ETOT    850000      // E + N self-loops
#define HH      2
#define CC      64
#define HC      128
#define BB      64
#define OUTC    2
#define NEG_SLOPE 0.2f
#define BN_EPS  1e-5f

#define NBLK_SCAN ((NN + 255) / 256)   // 196

// XCD binning for CSR build: 8 dst ranges, blockIdx%8 -> XCD (round-robin dispatch)
#define NXCD     8
#define NPX      ((NN + NXCD - 1) / NXCD)        // 6250 nodes per bin
#define EDGES_PER_SLOT 2048
#define NSLOT    ((ETOT + EDGES_PER_SLOT - 1) / EDGES_PER_SLOT)  // 416

typedef __bf16 bf16x8 __attribute__((ext_vector_type(8)));
typedef float  f32x4  __attribute__((ext_vector_type(4)));

__device__ __forceinline__ unsigned f2bf(float f) {
    __bf16 b = (__bf16)f;                      // RNE convert
    return (unsigned)__builtin_bit_cast(unsigned short, b);
}

// async global->LDS, 16B per lane; LDS dest is wave-uniform base + lane*16
__device__ __forceinline__ void gload_lds16(const float* g, float* l) {
    __builtin_amdgcn_global_load_lds(
        (const __attribute__((address_space(1))) unsigned*)g,
        (__attribute__((address_space(3))) unsigned*)l,
        16, 0, 0);
}

// ================= CSR build (XCD-binned: each XCD owns a dst range; atomics and
// esrc writes stay in one L2 — no cross-XCD line ping-pong / write amplification) ==========
__global__ __launch_bounds__(256) void deg_kernel(const int* __restrict__ ei, int* __restrict__ deg)
{
    const int xcd  = blockIdx.x & (NXCD - 1);
    const int slot = blockIdx.x >> 3;
    const int lo = xcd * NPX, hi = lo + NPX;
    const int base = slot * EDGES_PER_SLOT;
#pragma unroll
    for (int it = 0; it < EDGES_PER_SLOT / 256; ++it) {
        int e = base + it * 256 + threadIdx.x;
        if (e < ETOT) {
            int d = (e < EE) ? ei[EE + e] : (e - EE);
            if (d >= lo && d < hi) atomicAdd(&deg[d], 1);
        }
    }
}

// --- hierarchical scan ---
__global__ __launch_bounds__(256) void bsum_kernel(const int* __restrict__ deg, int* __restrict__ bsum)
{
    int i = blockIdx.x * 256 + threadIdx.x;
    int v = (i < NN) ? deg[i] : 0;
    int lane = threadIdx.x & 63, wv = threadIdx.x >> 6;
#pragma unroll
    for (int o = 32; o > 0; o >>= 1) v += __shfl_down(v, o);
    __shared__ int ws[4];
    if (lane == 0) ws[wv] = v;
    __syncthreads();
    if (threadIdx.x == 0) bsum[blockIdx.x] = ws[0] + ws[1] + ws[2] + ws[3];
}

__global__ __launch_bounds__(256) void bscan_kernel(
    const int* __restrict__ bsum, int* __restrict__ bofs, int* __restrict__ rowp)
{
    int t = threadIdx.x;
    int lane = t & 63, wv = t >> 6;
    int v = (t < NBLK_SCAN) ? bsum[t] : 0;
    int x = v;
#pragma unroll
    for (int o = 1; o < 64; o <<= 1) {
        int y = __shfl_up(x, o);
        if (lane >= o) x += y;
    }
    __shared__ int ws[4];
    if (lane == 63) ws[wv] = x;
    __syncthreads();
    int wo = 0;
#pragma unroll
    for (int w = 0; w < 4; ++w) if (w < wv) wo += ws[w];
    if (t < NBLK_SCAN) bofs[t] = x + wo - v;     // exclusive
    if (t == 0) rowp[NN] = ETOT;
}

__global__ __launch_bounds__(256) void bapply_kernel(
    const int* __restrict__ deg, const int* __restrict__ bofs,
    int* __restrict__ rowp, int* __restrict__ cur)
{
    int i = blockIdx.x * 256 + threadIdx.x;
    int v = (i < NN) ? deg[i] : 0;
    int lane = threadIdx.x & 63, wv = threadIdx.x >> 6;
    int x = v;
#pragma unroll
    for (int o = 1; o < 64; o <<= 1) {
        int y = __shfl_up(x, o);
        if (lane >= o) x += y;
    }
    __shared__ int ws[4];
    if (lane == 63) ws[wv] = x;
    __syncthreads();
    int wo = 0;
#pragma unroll
    for (int w = 0; w < 4; ++w) if (w < wv) wo += ws[w];
    if (i < NN) {
        int r = bofs[blockIdx.x] + x + wo - v;   // exclusive global
        rowp[i] = r; cur[i] = r;
    }
}

__global__ __launch_bounds__(256) void scatter_kernel(
    const int* __restrict__ ei, int* __restrict__ cur, int* __restrict__ esrc)
{
    const int xcd  = blockIdx.x & (NXCD - 1);
    const int slot = blockIdx.x >> 3;
    const int lo = xcd * NPX, hi = lo + NPX;
    const int base = slot * EDGES_PER_SLOT;
#pragma unroll
    for (int it = 0; it < EDGES_PER_SLOT / 256; ++it) {
        int e = base + it * 256 + threadIdx.x;
        if (e < ETOT) {
            int s, d;
            if (e < EE) { s = ei[e]; d = ei[EE + e]; }
            else        { s = e - EE; d = s; }
            if (d >= lo && d < hi) {
                int pos = atomicAdd(&cur[d], 1);
                esrc[pos] = s;
            }
        }
    }
}

// ================= W -> bf16 MFMA fragment order (both weights in one launch) ========
__global__ __launch_bounds__(256) void wfrag_kernel(
    const float* __restrict__ W1, unsigned short* __restrict__ Wf1,
    const float* __restrict__ W2, unsigned short* __restrict__ Wf2)
{
    int t = blockIdx.x * 256 + threadIdx.x;
    const float* W; unsigned short* Wf;
    if (t < IN_C * 16) { W = W1; Wf = Wf1; }
    else {
        t -= IN_C * 16;
        if (t >= HC * 16) return;
        W = W2; Wf = Wf2;
    }
    int lane = t & 63, frag = t >> 6;
    int kblk = frag >> 3, nt = frag & 7;
    int quad = lane >> 4, ln = lane & 15;
    int kbase = kblk * 32 + quad * 8;
    int n = nt * 16 + ln;
    unsigned short u[8];
#pragma unroll
    for (int j = 0; j < 8; ++j)
        u[j] = (unsigned short)f2bf(W[(size_t)(kbase + j) * HC + n]);
    ushort4 a; a.x = u[0]; a.y = u[1]; a.z = u[2]; a.w = u[3];
    ushort4 b; b.x = u[4]; b.y = u[5]; b.z = u[6]; b.w = u[7];
    *(ushort4*)(Wf + (size_t)t * 8)     = a;
    *(ushort4*)(Wf + (size_t)t * 8 + 4) = b;
}

// ================= LDS-staged MFMA GEMM, BK=64 per barrier =================
// Block = 64 rows x 128 cols, 4 waves. A staged via global_load_lds into a 2 x 16 KB
// double buffer, TWO 32-wide K-substeps per barrier: halves barrier count and gives
// each staged load ~16 MFMAs of compute to land under (the vmcnt(0) drain at
// __syncthreads is the structural stall of this schedule — amortize it).
// LDS sub-tile [64][32] XOR-swizzled via pre-swizzled global source (rule 21).
template<int K, bool AFFINE>
__global__ __launch_bounds__(256) void mfma_gemm_kernel(
    const float* __restrict__ A, const unsigned short* __restrict__ Wf,
    const float* __restrict__ atts, const float* __restrict__ attd,
    unsigned* __restrict__ hb, float* __restrict__ as_, float* __restrict__ ad_,
    const float* __restrict__ sc, const float* __restrict__ sh)
{
    constexpr int NSTEP = K >> 5;                   // 32-wide substeps
    __shared__ __align__(16) float Abuf[2][64 * 64]; // 2 x 16 KB

    const int tid  = threadIdx.x;
    const int wave = tid >> 6, lane = tid & 63;
    const int quad = lane >> 4, ln = lane & 15;
    const int m0 = blockIdx.x * 64;

    // staging geometry: thread t covers 16B slot (row t>>3, slot t&7), rows +0/+32
    const int srow = tid >> 3;
    const int g    = (tid & 7) ^ (srow & 7);        // swizzled source slot
    int grow0 = m0 + srow;      if (grow0 > NN - 1) grow0 = NN - 1;
    int grow1 = m0 + srow + 32; if (grow1 > NN - 1) grow1 = NN - 1;
    const float* gsrc0 = A + (size_t)grow0 * K + g * 4;
    const float* gsrc1 = A + (size_t)grow1 * K + g * 4;

    // fragment-read geometry
    const int rr = wave * 16 + ln;
    const int base_f = rr * 32;
    const int sA = (((quad * 2)     ^ (rr & 7)) * 4);
    const int sB = (((quad * 2 + 1) ^ (rr & 7)) * 4);

    const unsigned short* wbase = Wf + lane * 8;

    f32x4 acc[8];
#pragma unroll
    for (int nt = 0; nt < 8; ++nt) acc[nt] = (f32x4){0.f, 0.f, 0.f, 0.f};

    // prologue: stage substeps 0,1 into buf0; load B frags for ks=0
    gload_lds16(gsrc0,      &Abuf[0][wave * 256]);
    gload_lds16(gsrc1,      &Abuf[0][1024 + wave * 256]);
    gload_lds16(gsrc0 + 32, &Abuf[0][2048 + wave * 256]);
    gload_lds16(gsrc1 + 32, &Abuf[0][3072 + wave * 256]);
    bf16x8 bfr[2][8];
#pragma unroll
    for (int nt = 0; nt < 8; ++nt) bfr[0][nt] = *(const bf16x8*)(wbase + nt * 512);

#pragma unroll
    for (int ks = 0; ks < NSTEP; ++ks) {
        const int sub  = ks & 1;             // substep within BK=64
        const int cbuf = (ks >> 1) & 1;      // LDS buffer
        const int bsel = ks & 1;             // rolling B-frag buffer
        if (sub == 0) {
            // barrier drains vmcnt(0): stage(kb) loads issued a full BK-iter ago are in
            __syncthreads();
            if (ks + 2 < NSTEP) {
                const float* n0 = gsrc0 + (size_t)(ks + 2) * 32;
                const float* n1 = gsrc1 + (size_t)(ks + 2) * 32;
                float* db = &Abuf[cbuf ^ 1][wave * 256];
                gload_lds16(n0,      db);
                gload_lds16(n1,      db + 1024);
                gload_lds16(n0 + 32, db + 2048);
                gload_lds16(n1 + 32, db + 3072);
            }
        }

        const float* fb_base = &Abuf[cbuf][sub * 2048 + base_f];
        float4 fa = *(const float4*)(fb_base + sA);
        float4 fb = *(const float4*)(fb_base + sB);
        float va[8] = {fa.x, fa.y, fa.z, fa.w, fb.x, fb.y, fb.z, fb.w};
        if (AFFINE) {
            const int kk = ks * 32 + quad * 8;
            const float4 s0 = *(const float4*)(sc + kk), s1 = *(const float4*)(sc + kk + 4);
            const float4 h0 = *(const float4*)(sh + kk), h1 = *(const float4*)(sh + kk + 4);
            va[0] = fmaxf(fmaf(s0.x, va[0], h0.x), 0.f);
            va[1] = fmaxf(fmaf(s0.y, va[1], h0.y), 0.f);
            va[2] = fmaxf(fmaf(s0.z, va[2], h0.z), 0.f);
            va[3] = fmaxf(fmaf(s0.w, va[3], h0.w), 0.f);
            va[4] = fmaxf(fmaf(s1.x, va[4], h1.x), 0.f);
            va[5] = fmaxf(fmaf(s1.y, va[5], h1.y), 0.f);
            va[6] = fmaxf(fmaf(s1.z, va[6], h1.z), 0.f);
            va[7] = fmaxf(fmaf(s1.w, va[7], h1.w), 0.f);
        }
        union { bf16x8 v; unsigned short u[8]; } af;
#pragma unroll
        for (int j = 0; j < 8; ++j) af.u[j] = (unsigned short)f2bf(va[j]);

        // prefetch next substep's B-frags (L2-hot; in flight across this step's MFMAs)
        if (ks + 1 < NSTEP) {
            const unsigned short* wfp = wbase + (size_t)(ks + 1) * 4096;
#pragma unroll
            for (int nt = 0; nt < 8; ++nt)
                bfr[bsel ^ 1][nt] = *(const bf16x8*)(wfp + nt * 512);
        }

#pragma unroll
        for (int nt = 0; nt < 8; ++nt)
            acc[nt] = __builtin_amdgcn_mfma_f32_16x16x32_bf16(af.v, bfr[bsel][nt], acc[nt], 0, 0, 0);
    }

    // epilogue: pack bf16 pairs + fused attention logits; C/D layout col=ln, row=quad*4+r
    float wsv[8], wdv[8];
#pragma unroll
    for (int nt = 0; nt < 8; ++nt) { wsv[nt] = atts[nt * 16 + ln]; wdv[nt] = attd[nt * 16 + ln]; }

    const int mbase = m0 + wave * 16 + quad * 4;
#pragma unroll
    for (int r = 0; r < 4; ++r) {
        int m = mbase + r;
        bool ok = (m < NN);
        float ps0 = 0.f, ps1 = 0.f, pd0 = 0.f, pd1 = 0.f;
#pragma unroll
        for (int nt = 0; nt < 8; ++nt) {
            float v = acc[nt][r];
            if (nt < 4) { ps0 = fmaf(v, wsv[nt], ps0); pd0 = fmaf(v, wdv[nt], pd0); }
            else        { ps1 = fmaf(v, wsv[nt], ps1); pd1 = fmaf(v, wdv[nt], pd1); }
        }
#pragma unroll
        for (int nt = 0; nt < 4; ++nt) {
            unsigned pk = f2bf(acc[nt][r]) | (f2bf(acc[nt + 4][r]) << 16);
            if (ok) hb[(size_t)m * 64 + nt * 16 + ln] = pk;
        }
#pragma unroll
        for (int o = 8; o > 0; o >>= 1) {
            ps0 += __shfl_down(ps0, o); ps1 += __shfl_down(ps1, o);
            pd0 += __shfl_down(pd0, o); pd1 += __shfl_down(pd1, o);
        }
        if (ok && ln == 0) {
            *(float2*)&as_[m * 2] = make_float2(ps0, ps1);
            *(float2*)&ad_[m * 2] = make_float2(pd0, pd1);
        }
    }
}

// ================= fused segment-softmax + aggregate + BN-stats partials =============
// One wave per dst node (grid exactly covers N: no early return, block-wide sync ok).
// Gather loop unrolled 8-deep (avg degree ~17 -> 2-3 serial latency groups per node).
// Epilogue: block-level LDS reduction of the 4 nodes' out values -> 64-way-sliced
// global stats (sum, sumsq per channel); kills the separate 25.6MB bn_stats pass.
__global__ __launch_bounds__(256) void gat_agg_kernel(
    const int* __restrict__ rowp, const int* __restrict__ esrc,
    const float* __restrict__ as_, const float* __restrict__ ad_,
    const unsigned* __restrict__ hb, float* __restrict__ out,
    float* __restrict__ stats)
{
    const int tid  = threadIdx.x;
    const int node = (blockIdx.x * 256 + tid) >> 6;
    const int wave = tid >> 6;
    const int lane = tid & 63;
    int beg = rowp[node], end = rowp[node + 1];
    float2 adv = *(const float2*)&ad_[node * 2];

    float l0 = 0.f, l1 = 0.f, a0 = 0.f, a1 = 0.f;

    for (int j0 = beg; j0 < end; j0 += 64) {
        int nj = min(64, end - j0);
        int   sl  = 0;
        float p0l = 0.f, p1l = 0.f;
        if (j0 + lane < end) {
            sl = esrc[j0 + lane];
            float2 t = *(const float2*)&as_[sl * 2];
            float e0 = t.x + adv.x; e0 = fmaxf(e0, NEG_SLOPE * e0);
            float e1 = t.y + adv.y; e1 = fmaxf(e1, NEG_SLOPE * e1);
            p0l = __expf(e0); p1l = __expf(e1);
        }
        l0 += p0l; l1 += p1l;          // per-lane partial denominator

        int j = 0;
        for (; j + 8 <= nj; j += 8) {
            int s0 = __shfl(sl, j),     s1 = __shfl(sl, j + 1);
            int s2 = __shfl(sl, j + 2), s3 = __shfl(sl, j + 3);
            int s4 = __shfl(sl, j + 4), s5 = __shfl(sl, j + 5);
            int s6 = __shfl(sl, j + 6), s7 = __shfl(sl, j + 7);
            unsigned u0 = hb[(size_t)s0 * 64 + lane];
            unsigned u1 = hb[(size_t)s1 * 64 + lane];
            unsigned u2 = hb[(size_t)s2 * 64 + lane];
            unsigned u3 = hb[(size_t)s3 * 64 + lane];
            unsigned u4 = hb[(size_t)s4 * 64 + lane];
            unsigned u5 = hb[(size_t)s5 * 64 + lane];
            unsigned u6 = hb[(size_t)s6 * 64 + lane];
            unsigned u7 = hb[(size_t)s7 * 64 + lane];
            a0 = fmaf(__shfl(p0l, j    ), __uint_as_float(u0 << 16), a0);
            a1 = fmaf(__shfl(p1l, j    ), __uint_as_float(u0 & 0xffff0000u), a1);
            a0 = fmaf(__shfl(p0l, j + 1), __uint_as_float(u1 << 16), a0);
            a1 = fmaf(__shfl(p1l, j + 1), __uint_as_float(u1 & 0xffff0000u), a1);
            a0 = fmaf(__shfl(p0l, j + 2), __uint_as_float(u2 << 16), a0);
            a1 = fmaf(__shfl(p1l, j + 2), __uint_as_float(u2 & 0xffff0000u), a1);
            a0 = fmaf(__shfl(p0l, j + 3), __uint_as_float(u3 << 16), a0);
            a1 = fmaf(__shfl(p1l, j + 3), __uint_as_float(u3 & 0xffff0000u), a1);
            a0 = fmaf(__shfl(p0l, j + 4), __uint_as_float(u4 << 16), a0);
            a1 = fmaf(__shfl(p1l, j + 4), __uint_as_float(u4 & 0xffff0000u), a1);
            a0 = fmaf(__shfl(p0l, j + 5), __uint_as_float(u5 << 16), a0);
            a1 = fmaf(__shfl(p1l, j + 5), __uint_as_float(u5 & 0xffff0000u), a1);
            a0 = fmaf(__shfl(p0l, j + 6), __uint_as_float(u6 << 16), a0);
            a1 = fmaf(__shfl(p1l, j + 6), __uint_as_float(u6 & 0xffff0000u), a1);
            a0 = fmaf(__shfl(p0l, j + 7), __uint_as_float(u7 << 16), a0);
            a1 = fmaf(__shfl(p1l, j + 7), __uint_as_float(u7 & 0xffff0000u), a1);
        }
        for (; j + 2 <= nj; j += 2) {
            int sA = __shfl(sl, j), sB = __shfl(sl, j + 1);
            unsigned uA = hb[(size_t)sA * 64 + lane];
            unsigned uB = hb[(size_t)sB * 64 + lane];
            a0 = fmaf(__shfl(p0l, j    ), __uint_as_float(uA << 16), a0);
            a1 = fmaf(__shfl(p1l, j    ), __uint_as_float(uA & 0xffff0000u), a1);
            a0 = fmaf(__shfl(p0l, j + 1), __uint_as_float(uB << 16), a0);
            a1 = fmaf(__shfl(p1l, j + 1), __uint_as_float(uB & 0xffff0000u), a1);
        }
        if (j < nj) {
            int s = __shfl(sl, j);
            unsigned u = hb[(size_t)s * 64 + lane];
            a0 = fmaf(__shfl(p0l, j), __uint_as_float(u << 16), a0);
            a1 = fmaf(__shfl(p1l, j), __uint_as_float(u & 0xffff0000u), a1);
        }
    }

#pragma unroll
    for (int o = 1; o < 64; o <<= 1) {
        l0 += __shfl_xor(l0, o); l1 += __shfl_xor(l1, o);
    }
    float v0 = a0 / l0;
    float v1 = a1 / l1;
    out[(size_t)node * HC + lane]      = v0;
    out[(size_t)node * HC + 64 + lane] = v1;

    // ---- fused BN-stats partials ----
    __shared__ float red[4][256];
    red[wave][lane]      = v0;
    red[wave][64 + lane] = v1;
    __syncthreads();
    if (tid < 128) {
        float s = 0.f, q = 0.f;
#pragma unroll
        for (int w = 0; w < 4; ++w) {
            float v = red[w][tid];
            s += v; q = fmaf(v, v, q);
        }
        int slot = blockIdx.x & 63;
        atomicAdd(&stats[slot * 128 + tid], s);
        atomicAdd(&stats[64 * 128 + slot * 128 + tid], q);
    }
}

// ================= BN params: reduce 64 stat slices =================
__global__ void bn_params_kernel(
    const float* __restrict__ stats, const float* __restrict__ gamma,
    const float* __restrict__ beta, float* __restrict__ sc, float* __restrict__ sh)
{
    int c = threadIdx.x;                  // 128 threads
    float su = 0.f, sq = 0.f;
#pragma unroll
    for (int k = 0; k < 64; ++k) {
        su += stats[k * 128 + c];
        sq += stats[64 * 128 + k * 128 + c];
    }
    const float inv_n = 1.0f / (float)NN;
    float mu = su * inv_n;
    float var = sq * inv_n - mu * mu;
    float rs = rsqrtf(var + BN_EPS);
    float s = gamma[c] * rs;
    sc[c] = s;
    sh[c] = beta[c] - mu * s;
}

// ================= pool: 64 rows/block (782 blocks), flush-on-graph-change =================
__global__ __launch_bounds__(256) void pool_kernel(
    const float* __restrict__ x, const float* __restrict__ sc,
    const float* __restrict__ sh, const int* __restrict__ batch,
    float* __restrict__ pool, float* __restrict__ cnt)
{
    int c = threadIdx.x & 127;
    int half = threadIdx.x >> 7;
    int r0 = blockIdx.x * 64;
    int rend = min(r0 + 64, NN);
    float s = sc[c], b = sh[c];
    int cur = -1; float acc = 0.f, ccount = 0.f;
    for (int r = r0 + half; r < rend; r += 2) {
        int g = batch[r];
        if (g != cur) {
            if (cur >= 0) {
                atomicAdd(&pool[cur * HC + c], acc);
                if (c == 0) atomicAdd(&cnt[cur], ccount);
            }
            cur = g; acc = 0.f; ccount = 0.f;
        }
        float v = x[(size_t)r * HC + c];
        acc += fmaxf(fmaf(s, v, b), 0.f);
        ccount += 1.f;
    }
    if (cur >= 0) {
        atomicAdd(&pool[cur * HC + c], acc);
        if (c == 0) atomicAdd(&cnt[cur], ccount);
    }
}

// ================= final linear: [64,128]@[128,2] + blin =================
__global__ void final_kernel(
    const float* __restrict__ pool, const float* __restrict__ cnt,
    const float* __restrict__ Wlin, const float* __restrict__ blin,
    float* __restrict__ outp)
{
    int t = threadIdx.x;               // 128 threads
    int b = t >> 1, oc = t & 1;
    float inv = 1.f / fmaxf(cnt[b], 1.f);
    float s = blin[oc];
    for (int c = 0; c < HC; ++c)
        s += pool[b * HC + c] * inv * Wlin[c * 2 + oc];
    outp[b * 2 + oc] = s;
}

// ================= workspace layout =================
// floats
static constexpr size_t OFF_OUT   = 0;                        // [N*HC]
static constexpr size_t OFF_AS    = OFF_OUT + (size_t)NN*HC;  // [N*2]
static constexpr size_t OFF_AD    = OFF_AS  + (size_t)NN*HH;
static constexpr size_t OFF_ST1   = OFF_AD  + (size_t)NN*HH;  // zero from here: [2*64*128]
static constexpr size_t OFF_ST2   = OFF_ST1 + 2*64*128;
static constexpr size_t OFF_SC1   = OFF_ST2 + 2*64*128;       // [128]
static constexpr size_t OFF_SH1   = OFF_SC1 + 128;
static constexpr size_t OFF_SC2   = OFF_SH1 + 128;
static constexpr size_t OFF_SH2   = OFF_SC2 + 128;
static constexpr size_t OFF_POOL  = OFF_SH2 + 128;            // [B*HC]
static constexpr size_t OFF_CNT   = OFF_POOL+ (size_t)BB*HC;  // [B]
static constexpr size_t OFF_ZEND  = OFF_CNT + BB;             // end of zeroed float region
// ints (after float region) — deg FIRST so one memset covers floats+deg
static constexpr size_t IOFF_DEG  = 0;                        // [N]  (zeroed)
static constexpr size_t IOFF_ROWP = IOFF_DEG  + NN;           // [N+1]
static constexpr size_t IOFF_CUR  = IOFF_ROWP + NN + 1;       // [N]
static constexpr size_t IOFF_BSUM = IOFF_CUR  + NN;           // [NBLK_SCAN]
static constexpr size_t IOFF_BOFS = IOFF_BSUM + NBLK_SCAN;    // [NBLK_SCAN]
static constexpr size_t IOFF_ESRC = IOFF_BOFS + NBLK_SCAN;    // [ETOT]
static constexpr size_t IOFF_HB   = (IOFF_ESRC + ETOT + 3) & ~(size_t)3;  // [N*64] uints
static constexpr size_t IOFF_WF1  = IOFF_HB + (size_t)NN*64;  // [512*64] ints
static constexpr size_t IOFF_WF2  = IOFF_WF1 + (size_t)IN_C*64; // [128*64] ints
static constexpr size_t IOFF_END  = IOFF_WF2 + (size_t)HC*64;

extern "C" void kernel_launch(void* const* d_in, const int* in_sizes, int n_in,
                              void* d_out, int out_size, void* d_ws, size_t ws_size,
                              hipStream_t stream)
{
    const float* x       = (const float*)d_in[0];
    const int*   ei      = (const int*)  d_in[1];
    const int*   batch   = (const int*)  d_in[2];
    const float* W1      = (const float*)d_in[3];
    const float* atts1   = (const float*)d_in[4];
    const float* attd1   = (const float*)d_in[5];
    const float* gamma1  = (const float*)d_in[7];
    const float* beta1   = (const float*)d_in[8];
    const float* W2      = (const float*)d_in[9];
    const float* atts2   = (const float*)d_in[10];
    const float* attd2   = (const float*)d_in[11];
    const float* gamma2  = (const float*)d_in[13];
    const float* beta2   = (const float*)d_in[14];
    const float* Wlin    = (const float*)d_in[15];
    const float* blin    = (const float*)d_in[16];
    float* outp = (float*)d_out;

    float* ws    = (float*)d_ws;
    float* out   = ws + OFF_OUT;
    float* as_   = ws + OFF_AS;
    float* ad_   = ws + OFF_AD;
    float* st1   = ws + OFF_ST1;
    float* st2   = ws + OFF_ST2;
    float* sc1   = ws + OFF_SC1;
    float* sh1   = ws + OFF_SH1;
    float* sc2   = ws + OFF_SC2;
    float* sh2   = ws + OFF_SH2;
    float* pool  = ws + OFF_POOL;
    float* cnt   = ws + OFF_CNT;

    int* iws  = (int*)(ws + OFF_ZEND);
    int* deg  = iws + IOFF_DEG;
    int* rowp = iws + IOFF_ROWP;
    int* curp = iws + IOFF_CUR;
    int* bsum = iws + IOFF_BSUM;
    int* bofs = iws + IOFF_BOFS;
    int* esrc = iws + IOFF_ESRC;
    unsigned* hb = (unsigned*)(iws + IOFF_HB);
    unsigned short* Wf1 = (unsigned short*)(iws + IOFF_WF1);
    unsigned short* Wf2 = (unsigned short*)(iws + IOFF_WF2);

    const int BIN_BLK   = NXCD * NSLOT;          // 8 * 416 = 3328
    const int GEMM_BLK  = (NN + 63) / 64;        // 782: 64 rows x 128 cols
    const int WAVE_BLK  = (NN + 3) / 4;          // 1 wave per node, 4 waves/block
    const int POOL_BLK  = (NN + 63) / 64;        // 782: 64 rows/block
    const int WFRG_BLK  = (IN_C * 16 + HC * 16 + 255) / 256;  // 40

    // single memset: bn-stats/sc-sh/pool/cnt float region + deg (contiguous)
    hipMemsetAsync(st1, 0, (OFF_ZEND - OFF_ST1) * sizeof(float) + NN * sizeof(int), stream);

    // ----- weight fragment packs + CSR build (shared by both layers) -----
    wfrag_kernel<<<WFRG_BLK, 256, 0, stream>>>(W1, Wf1, W2, Wf2);
    deg_kernel<<<BIN_BLK, 256, 0, stream>>>(ei, deg);
    bsum_kernel<<<NBLK_SCAN, 256, 0, stream>>>(deg, bsum);
    bscan_kernel<<<1, 256, 0, stream>>>(bsum, bofs, rowp);
    bapply_kernel<<<NBLK_SCAN, 256, 0, stream>>>(deg, bofs, rowp, curp);
    scatter_kernel<<<BIN_BLK, 256, 0, stream>>>(ei, curp, esrc);

    // ----- layer 1 (GEMM + fused alpha + bf16 pack; agg + fused BN stats) -----
    mfma_gemm_kernel<IN_C, false><<<GEMM_BLK, 256, 0, stream>>>(
        x, Wf1, atts1, attd1, hb, as_, ad_, nullptr, nullptr);
    gat_agg_kernel<<<WAVE_BLK, 256, 0, stream>>>(rowp, esrc, as_, ad_, hb, out, st1);
    bn_params_kernel<<<1, 128, 0, stream>>>(st1, gamma1, beta1, sc1, sh1);

    // ----- layer 2 (BN1-affine+ReLU fused into GEMM2 A-load) -----
    mfma_gemm_kernel<HC, true><<<GEMM_BLK, 256, 0, stream>>>(
        out, Wf2, atts2, attd2, hb, as_, ad_, sc1, sh1);
    gat_agg_kernel<<<WAVE_BLK, 256, 0, stream>>>(rowp, esrc, as_, ad_, hb, out, st2);
    bn_params_kernel<<<1, 128, 0, stream>>>(st2, gamma2, beta2, sc2, sh2);

    // ----- pool + final linear -----
    pool_kernel<<<POOL_BLK, 256, 0, stream>>>(out, sc2, sh2, batch, pool, cnt);
    final_kernel<<<1, 128, 0, stream>>>(pool, cnt, Wlin, blin, outp);
}